// Round 14
// baseline (961.892 us; speedup 1.0000x reference)
//
#include <hip/hip_runtime.h>
#include <stddef.h>
#include <stdint.h>

#define N_NODES 50000
#define N_EDGES 800000
#define NF 96
#define FE 64
#define DIN 256
#define DOUT 192
#define BN_EPS 1e-5f
#define NT32 (N_EDGES / 32)        // 25000 tile-32 tiles
#define SSTRIDE 4
#define NSAMP (NT32 / SSTRIDE)     // 6250 tiles = 200000 edges

typedef float f32x4 __attribute__((ext_vector_type(4)));
typedef short bf16x8 __attribute__((ext_vector_type(8)));

__device__ __forceinline__ unsigned short f2bf(float f) {
  unsigned int u = __float_as_uint(f);
  return (unsigned short)((u + 0x7fffu + ((u >> 16) & 1u)) >> 16);
}
__device__ __forceinline__ float sigmoidf_(float x) {
  return 1.f / (1.f + __expf(-x));
}
__device__ __forceinline__ float softplusf_(float x) {
  float t = exp2f(-fabsf(x) * 1.44269504f);
  return fmaxf(x, 0.f) + 0.69314718f * log2f(1.f + t);
}

// tile-32 row perm: A-row r (= rf*16 + hi*4 + j) holds sorted-edge
// e0 + hi*8 + rf*4 + j  => thread (hi) owns 8 CONSECUTIVE sorted edges.
__device__ __forceinline__ int rperm32_(int r) {
  return ((r >> 2) & 3) * 8 + (r >> 4) * 4 + (r & 3);
}

// our col c' = cblk*16+lm -> orig col: cblk even -> gate (cblk/2)*16+lm ;
// cblk odd -> conv 96+(cblk/2)*16+lm  (gate/conv paired in-lane per wave)
__device__ __forceinline__ int col_perm(int c) {
  int t = c >> 4, lm = c & 15;
  return (t >> 1) * 16 + (t & 1) * 96 + lm;
}

// ---------------- conversion / sort kernels ----------------
__global__ void k_cvt(const float* __restrict__ in, unsigned short* __restrict__ out, int n4) {
  int stride = gridDim.x * blockDim.x;
  for (int i = blockIdx.x * blockDim.x + threadIdx.x; i < n4; i += stride) {
    float4 v = reinterpret_cast<const float4*>(in)[i];
    ushort4 o;
    o.x = f2bf(v.x); o.y = f2bf(v.y); o.z = f2bf(v.z); o.w = f2bf(v.w);
    reinterpret_cast<ushort4*>(out)[i] = o;
  }
}

// edge features converted INTO SORTED ORDER: ebs[p] = bf16(edge[perm[p]])
__global__ void k_cvt_es(const float* __restrict__ edge, const int* __restrict__ perm,
                         unsigned short* __restrict__ ebs) {
  int stride = gridDim.x * blockDim.x;
  for (int i = blockIdx.x * blockDim.x + threadIdx.x; i < N_EDGES * 16; i += stride) {
    int p = i >> 4, c = i & 15;
    int e = perm[p];
    float4 v = reinterpret_cast<const float4*>(edge + (size_t)e * FE)[c];
    ushort4 o;
    o.x = f2bf(v.x); o.y = f2bf(v.y); o.z = f2bf(v.z); o.w = f2bf(v.w);
    reinterpret_cast<ushort4*>(ebs + (size_t)p * FE)[c] = o;
  }
}

__global__ void k_cvt_w(const float* __restrict__ W, unsigned short* __restrict__ Wt) {
  int i = blockIdx.x * blockDim.x + threadIdx.x;
  if (i < DOUT * DIN) {
    int c = i / DIN, k = i % DIN;
    Wt[i] = f2bf(W[k * DOUT + col_perm(c)]);
  }
}

__global__ void k_hist(const int* __restrict__ idx1, int* __restrict__ icounts) {
  int stride = gridDim.x * blockDim.x;
  for (int e = blockIdx.x * blockDim.x + threadIdx.x; e < N_EDGES; e += stride)
    atomicAdd(&icounts[idx1[e]], 1);
}

// ---- 3-phase multi-block exclusive scan of icounts[50000] -> offsets ----
#define SCAN_B 512
#define SCAN_NB 98
__global__ void k_scanA(const int* __restrict__ ic, int* __restrict__ off,
                        int* __restrict__ bsum) {
  __shared__ int tmp[SCAN_B];
  int tid = threadIdx.x, i = blockIdx.x * SCAN_B + tid;
  int v = (i < N_NODES) ? ic[i] : 0;
  tmp[tid] = v;
  __syncthreads();
  for (int o = 1; o < SCAN_B; o <<= 1) {
    int t = (tid >= o) ? tmp[tid - o] : 0;
    __syncthreads();
    tmp[tid] += t;
    __syncthreads();
  }
  if (i < N_NODES) off[i] = tmp[tid] - v;
  if (tid == SCAN_B - 1) bsum[blockIdx.x] = tmp[tid];
}
__global__ void k_scanB(const int* __restrict__ bsum, int* __restrict__ boff) {
  __shared__ int tmp[128];
  int tid = threadIdx.x;
  int v = (tid < SCAN_NB) ? bsum[tid] : 0;
  tmp[tid] = v;
  __syncthreads();
  for (int o = 1; o < 128; o <<= 1) {
    int t = (tid >= o) ? tmp[tid - o] : 0;
    __syncthreads();
    tmp[tid] += t;
    __syncthreads();
  }
  if (tid < SCAN_NB) boff[tid] = tmp[tid] - v;
}
__global__ void k_scanC(int* __restrict__ off, const int* __restrict__ boff) {
  int i = blockIdx.x * SCAN_B + threadIdx.x;
  if (i < N_NODES) off[i] += boff[blockIdx.x];
}

// scatter edge ids into sorted-by-idx1 order; also pre-gather idx2
__global__ void k_perm(const int* __restrict__ idx1, const int* __restrict__ idx2,
                       const int* __restrict__ offsets, int* __restrict__ cursor,
                       int* __restrict__ perm, int* __restrict__ i1s,
                       int* __restrict__ i2s) {
  int stride = gridDim.x * blockDim.x;
  for (int e = blockIdx.x * blockDim.x + threadIdx.x; e < N_EDGES; e += stride) {
    int n = idx1[e];
    int p = offsets[n] + atomicAdd(&cursor[n], 1);
    perm[p] = e;
    i1s[p] = n;
    i2s[p] = idx2[e];
  }
}

// ---------------- shared GEMM machinery (tile-32) ----------------
// 6 waves x 32 cols; 32 rows/tile; W(bf16) in 64 VGPR/wave; A double-buffered
// 2 x 16KB LDS; one barrier/tile; reg-prefetch of next tile (sv[3]).

#define GEMM_PROLOGUE()                                                        \
  const int tid = threadIdx.x;                                                 \
  const int lane = tid & 63;                                                   \
  const int w = tid >> 6;                                                      \
  const int lm = lane & 15;                                                    \
  const int hi = lane >> 4;                                                    \
  const int base_c = w * 32;                                                   \
  bf16x8 breg[2][8];                                                           \
  _Pragma("unroll") for (int ct = 0; ct < 2; ++ct)                             \
  _Pragma("unroll") for (int ks = 0; ks < 8; ++ks)                             \
      breg[ct][ks] = *reinterpret_cast<const bf16x8*>(                         \
          Wt + (size_t)(base_c + ct * 16 + lm) * DIN + ks * 32 + hi * 8);      \
  uint4 sv[3];

#define LOAD_TILE(T)                                                           \
  {                                                                            \
    const int e0_ = (T) * 32;                                                  \
    _Pragma("unroll") for (int k = 0; k < 3; ++k) {                            \
      int i = tid + k * 384;                                                   \
      if (i < 1024) {                                                          \
        int r = i >> 5, cs = i & 31;                                           \
        int es = e0_ + rperm32_(r);                                            \
        int i1 = i1s[es];                                                      \
        int i2 = i2s[es];                                                      \
        const unsigned short* s0 = nb + (size_t)i1 * NF + cs * 8;              \
        const unsigned short* s1 = nb + (size_t)i2 * NF + (cs - 12) * 8;       \
        const unsigned short* s2 = ebs + (size_t)es * FE + (cs - 24) * 8;      \
        const unsigned short* src = cs < 12 ? s0 : (cs < 24 ? s1 : s2);        \
        sv[k] = *reinterpret_cast<const uint4*>(src);                          \
      }                                                                        \
    }                                                                          \
  }

#define WRITE_TILE(P)                                                          \
  _Pragma("unroll") for (int k = 0; k < 3; ++k) {                              \
    int i = tid + k * 384;                                                     \
    if (i < 1024) {                                                            \
      int r = i >> 5, cs = i & 31;                                             \
      *reinterpret_cast<uint4*>(&As[P][r * 256 + ((cs ^ (r & 7)) * 8)]) = sv[k]; \
    }                                                                          \
  }

#define COMPUTE_TILE(P)                                                        \
  _Pragma("unroll") for (int ks = 0; ks < 8; ++ks) {                           \
    bf16x8 a[2];                                                               \
    _Pragma("unroll") for (int rf = 0; rf < 2; ++rf) {                         \
      int row = rf * 16 + lm;                                                  \
      int slot = (ks * 4 + hi) ^ (lm & 7);                                     \
      a[rf] = *reinterpret_cast<const bf16x8*>(&As[P][row * 256 + slot * 8]);  \
    }                                                                          \
    _Pragma("unroll") for (int rf = 0; rf < 2; ++rf)                           \
      _Pragma("unroll") for (int ct = 0; ct < 2; ++ct)                         \
        acc[rf][ct] = __builtin_amdgcn_mfma_f32_16x16x32_bf16(                 \
            a[rf], breg[ct][ks], acc[rf][ct], 0, 0, 0);                        \
  }

// PASS 0: column stats of y = XW over stride-4 tile subsample (200k edges)
__global__ __launch_bounds__(384, 5) void k_gstats(
    const unsigned short* __restrict__ nb, const unsigned short* __restrict__ ebs,
    const unsigned short* __restrict__ Wt, const int* __restrict__ i1s,
    const int* __restrict__ i2s, float* __restrict__ colsum,
    float* __restrict__ colsumsq) {
  __shared__ unsigned short As[2][32 * 256];  // 32 KB
  GEMM_PROLOGUE();
  float s1a[2] = {0.f, 0.f}, s2a[2] = {0.f, 0.f};

  int s = blockIdx.x;
  int p = 0;
  if (s < NSAMP) LOAD_TILE(s * SSTRIDE);
  for (; s < NSAMP; s += gridDim.x) {
    WRITE_TILE(p);
    __syncthreads();
    int ns = s + gridDim.x;
    if (ns < NSAMP) LOAD_TILE(ns * SSTRIDE);

    f32x4 acc[2][2];
#pragma unroll
    for (int rf = 0; rf < 2; ++rf)
#pragma unroll
      for (int ct = 0; ct < 2; ++ct) acc[rf][ct] = (f32x4)(0.f);
    COMPUTE_TILE(p);

#pragma unroll
    for (int ct = 0; ct < 2; ++ct)
#pragma unroll
      for (int rf = 0; rf < 2; ++rf)
#pragma unroll
        for (int j = 0; j < 4; ++j) {
          float y = acc[rf][ct][j];
          s1a[ct] += y;
          s2a[ct] += y * y;
        }
    p ^= 1;
  }

#pragma unroll
  for (int ct = 0; ct < 2; ++ct) {
    float s1 = s1a[ct], s2 = s2a[ct];
    s1 += __shfl_xor(s1, 16); s2 += __shfl_xor(s2, 16);
    s1 += __shfl_xor(s1, 32); s2 += __shfl_xor(s2, 32);
    if (lane < 16) {
      atomicAdd(&colsum[base_c + ct * 16 + lane], s1);
      atomicAdd(&colsumsq[base_c + ct * 16 + lane], s2);
    }
  }
}

// PASS 1: zhat = y*a1 + b1f; msg = sigmoid(gate)*softplus(conv);
// in-register segmented scatter (thread holds 8 consecutive sorted edges)
__global__ __launch_bounds__(384, 5) void k_gmsg2(
    const unsigned short* __restrict__ nb, const unsigned short* __restrict__ ebs,
    const unsigned short* __restrict__ Wt, const int* __restrict__ i1s,
    const int* __restrict__ i2s, const float* __restrict__ a1,
    const float* __restrict__ b1f, float* __restrict__ sums) {
  __shared__ unsigned short As[2][32 * 256];  // 32 KB
  GEMM_PROLOGUE();
  float c0[2], c1[2];
#pragma unroll
  for (int ct = 0; ct < 2; ++ct) {
    c0[ct] = a1[base_c + ct * 16 + lm];
    c1[ct] = b1f[base_c + ct * 16 + lm];
  }

  int tile = blockIdx.x;
  int p = 0;
  if (tile < NT32) LOAD_TILE(tile);
  for (; tile < NT32; tile += gridDim.x) {
    const int e0 = tile * 32;
    WRITE_TILE(p);
    __syncthreads();
    int nt = tile + gridDim.x;
    if (nt < NT32) LOAD_TILE(nt);

    f32x4 acc[2][2];
#pragma unroll
    for (int rf = 0; rf < 2; ++rf)
#pragma unroll
      for (int ct = 0; ct < 2; ++ct) acc[rf][ct] = (f32x4)(0.f);
    COMPUTE_TILE(p);

    // node ids for this thread's 8 consecutive sorted edges (32B-aligned)
    const int4* ip = reinterpret_cast<const int4*>(&i1s[e0 + hi * 8]);
    int4 n0 = ip[0], n1 = ip[1];
    int nidv[8] = {n0.x, n0.y, n0.z, n0.w, n1.x, n1.y, n1.z, n1.w};

    const int mcol = w * 16 + lm;
    float run = 0.f;
    int curn = nidv[0];
#pragma unroll
    for (int rf = 0; rf < 2; ++rf)
#pragma unroll
      for (int j = 0; j < 4; ++j) {
        int k = rf * 4 + j;
        float zg = acc[rf][0][j] * c0[0] + c1[0];
        float zc = acc[rf][1][j] * c0[1] + c1[1];
        run += sigmoidf_(zg) * softplusf_(zc);
        int nxt = (k < 7) ? nidv[(k + 1) & 7] : -1;
        if (nxt != curn) {
          atomicAdd(&sums[(size_t)curn * NF + mcol], run);
          run = 0.f;
          curn = nxt;
        }
      }
    p ^= 1;
  }
}

// ---------------- BN affine computation ----------------
// stats from the 200k-edge subsample (unbiased estimators of batch stats)
__global__ void k_bn1(const float* __restrict__ colsum, const float* __restrict__ colsumsq,
                      const float* __restrict__ gamma1, const float* __restrict__ beta1,
                      float* __restrict__ a1, float* __restrict__ b1f) {
  int c = threadIdx.x;  // 192, our col space
  int o = col_perm(c);
  const float inv_n = 1.f / (float)(NSAMP * 32);
  float my = colsum[c] * inv_n;
  float v = colsumsq[c] * inv_n - my * my;
  float a = gamma1[o] * rsqrtf(v + BN_EPS);
  a1[c] = a;
  b1f[c] = beta1[o] - my * a;  // bias cancels against batch mean
}

__global__ void k_nodestats(const float* __restrict__ sums, const int* __restrict__ icounts,
                            float* __restrict__ colsum2, float* __restrict__ colsumsq2) {
  __shared__ float sh[2][2][96];
  int t = threadIdx.x;  // 192
  int c = t % 96, sub = t / 96;
  float s1 = 0.f, s2 = 0.f;
  int n0 = blockIdx.x * 256;
  for (int r = sub; r < 256; r += 2) {
    int n = n0 + r;
    if (n < N_NODES) {
      float v = sums[(size_t)n * NF + c] / fmaxf((float)icounts[n], 1.f);
      s1 += v; s2 += v * v;
    }
  }
  sh[0][sub][c] = s1; sh[1][sub][c] = s2;
  __syncthreads();
  if (sub == 0) {
    atomicAdd(&colsum2[c], s1 + sh[0][1][c]);
    atomicAdd(&colsumsq2[c], s2 + sh[1][1][c]);
  }
}

__global__ void k_bn2(const float* __restrict__ colsum2, const float* __restrict__ colsumsq2,
                      const float* __restrict__ gamma2, const float* __restrict__ beta2,
                      float* __restrict__ a2, float* __restrict__ b2f) {
  int c = threadIdx.x;
  if (c < 96) {
    float m = colsum2[c] * (1.f / N_NODES);
    float v = colsumsq2[c] * (1.f / N_NODES) - m * m;
    float a = gamma2[c] * rsqrtf(v + BN_EPS);
    a2[c] = a;
    b2f[c] = beta2[c] - m * a;
  }
}

__global__ void k_final(const float* __restrict__ node, const float* __restrict__ sums,
                        const int* __restrict__ icounts, const float* __restrict__ a2,
                        const float* __restrict__ b2f, float* __restrict__ out) {
  int stride = gridDim.x * blockDim.x;
  for (int i = blockIdx.x * blockDim.x + threadIdx.x; i < N_NODES * NF / 4; i += stride) {
    int n = i / 24, c4 = (i % 24) * 4;
    float inv = 1.f / fmaxf((float)icounts[n], 1.f);
    float4 s = reinterpret_cast<const float4*>(sums)[i];
    float4 nf = reinterpret_cast<const float4*>(node)[i];
    float4 o;
    o.x = softplusf_(nf.x + s.x * inv * a2[c4 + 0] + b2f[c4 + 0]);
    o.y = softplusf_(nf.y + s.y * inv * a2[c4 + 1] + b2f[c4 + 1]);
    o.z = softplusf_(nf.z + s.z * inv * a2[c4 + 2] + b2f[c4 + 2]);
    o.w = softplusf_(nf.w + s.w * inv * a2[c4 + 3] + b2f[c4 + 3]);
    reinterpret_cast<float4*>(out)[i] = o;
  }
}

extern "C" void kernel_launch(void* const* d_in, const int* in_sizes, int n_in,
                              void* d_out, int out_size, void* d_ws, size_t ws_size,
                              hipStream_t stream) {
  const float* node = (const float*)d_in[0];
  const float* edge = (const float*)d_in[1];
  const float* W = (const float*)d_in[2];
  const float* gamma1 = (const float*)d_in[4];
  const float* beta1 = (const float*)d_in[5];
  const float* gamma2 = (const float*)d_in[6];
  const float* beta2 = (const float*)d_in[7];
  const int* idx1 = (const int*)d_in[8];
  const int* idx2 = (const int*)d_in[9];
  float* out = (float*)d_out;

  char* ws = (char*)d_ws;
  unsigned short* nb = (unsigned short*)(ws);               //   9,600,000
  unsigned short* ebs = (unsigned short*)(ws + 9600000);    // 102,400,000 (sorted)
  unsigned short* Wt = (unsigned short*)(ws + 112000000);   //      98,304
  float* sums = (float*)(ws + 112098304);                   //  19,200,000
  float* stats = (float*)(ws + 131298304);                  //       8,192
  int* icounts = (int*)(ws + 131306496);                    //     200,000
  int* perm = (int*)(ws + 131506496);                       //   3,200,000
  int* i1s = (int*)(ws + 134706496);                        //   3,200,000
  int* i2s = (int*)(ws + 137906496);                        //   3,200,000
  // total 141,106,496 bytes

  // overlay at head of sums (used only before k_gmsg2, re-zeroed after)
  int* offsets = (int*)(ws + 112098304);        // 50000 ints
  int* cursor = offsets + 50048;                // 50000 ints

  float* colsum1 = stats;          // 192
  float* colsumsq1 = stats + 192;  // 192
  float* colsum2 = stats + 384;    // 96
  float* colsumsq2 = stats + 480;  // 96
  float* a1 = stats + 576;         // 192
  float* b1f = stats + 768;        // 192
  float* a2 = stats + 960;         // 96
  float* b2f = stats + 1056;       // 96
  int* bsum = (int*)(ws + 131303424);  // 128 ints
  int* boff = (int*)(ws + 131303936);  // 128 ints

  // zero sums (incl. offsets/cursor overlay) + stats + icounts
  (void)hipMemsetAsync(ws + 112098304, 0, 19200000 + 8192 + 200000, stream);

  k_cvt<<<2048, 256, 0, stream>>>(node, nb, N_NODES * NF / 4);
  k_cvt_w<<<DOUT * DIN / 256, 256, 0, stream>>>(W, Wt);
  k_hist<<<1024, 256, 0, stream>>>(idx1, icounts);
  k_scanA<<<SCAN_NB, SCAN_B, 0, stream>>>(icounts, offsets, bsum);
  k_scanB<<<1, 128, 0, stream>>>(bsum, boff);
  k_scanC<<<SCAN_NB, SCAN_B, 0, stream>>>(offsets, boff);
  k_perm<<<1024, 256, 0, stream>>>(idx1, idx2, offsets, cursor, perm, i1s, i2s);
  k_cvt_es<<<2048, 256, 0, stream>>>(edge, perm, ebs);

  k_gstats<<<2048, 384, 0, stream>>>(nb, ebs, Wt, i1s, i2s, colsum1, colsumsq1);
  k_bn1<<<1, 192, 0, stream>>>(colsum1, colsumsq1, gamma1, beta1, a1, b1f);

  // re-zero the overlay region before atomic accumulation into sums
  (void)hipMemsetAsync(ws + 112098304, 0, 524288, stream);

  k_gmsg2<<<2048, 384, 0, stream>>>(nb, ebs, Wt, i1s, i2s, a1, b1f, sums);

  k_nodestats<<<(N_NODES + 255) / 256, 192, 0, stream>>>(sums, icounts, colsum2, colsumsq2);
  k_bn2<<<1, 128, 0, stream>>>(colsum2, colsumsq2, gamma2, beta2, a2, b2f);
  k_final<<<2048, 256, 0, stream>>>(node, sums, icounts, a2, b2f, out);
}

// Round 15
// 753.032 us; speedup vs baseline: 1.2774x; 1.2774x over previous
//
#include <hip/hip_runtime.h>
#include <stddef.h>
#include <stdint.h>

#define N_NODES 50000
#define N_EDGES 800000
#define NF 96
#define FE 64
#define DIN 256
#define DOUT 192
#define BN_EPS 1e-5f
#define NTILES (N_EDGES / 64)
#define SSTRIDE 4                  // stats subsample: every 4th tile
#define NSAMP (NTILES / SSTRIDE)   // 3125 tiles = 200000 edges

typedef float f32x4 __attribute__((ext_vector_type(4)));
typedef short bf16x8 __attribute__((ext_vector_type(8)));

__device__ __forceinline__ unsigned short f2bf(float f) {
  unsigned int u = __float_as_uint(f);
  return (unsigned short)((u + 0x7fffu + ((u >> 16) & 1u)) >> 16);
}
__device__ __forceinline__ float sigmoidf_(float x) {
  return 1.f / (1.f + __expf(-x));
}
__device__ __forceinline__ float softplusf_(float x) {
  float t = exp2f(-fabsf(x) * 1.44269504f);
  return fmaxf(x, 0.f) + 0.69314718f * log2f(1.f + t);
}

// row permutation: A-row r holds sorted-edge e0 + rperm_(r); swaps rf<->hi so a
// thread's 16 C-fragment values are 16 CONSECUTIVE sorted edges.
__device__ __forceinline__ int rperm_(int r) {
  return ((r >> 2) & 3) * 16 + (r >> 4) * 4 + (r & 3);
}

// 12-wave col mapping: our col c' = w*16 + l (w in [0,12), l in [0,16)).
// l<8 -> gate col w*8+l ; l>=8 -> conv col 96 + w*8 + (l-8).
// => lane lm and lane lm+8 of wave w hold a gate/conv PAIR (shfl_xor(8)).
__device__ __forceinline__ int col_perm12(int c) {
  int w = c >> 4, l = c & 15;
  return (l < 8) ? (w * 8 + l) : (96 + w * 8 + l - 8);
}

// ---------------- conversion / sort kernels ----------------
__global__ void k_cvt(const float* __restrict__ in, unsigned short* __restrict__ out, int n4) {
  int stride = gridDim.x * blockDim.x;
  for (int i = blockIdx.x * blockDim.x + threadIdx.x; i < n4; i += stride) {
    float4 v = reinterpret_cast<const float4*>(in)[i];
    ushort4 o;
    o.x = f2bf(v.x); o.y = f2bf(v.y); o.z = f2bf(v.z); o.w = f2bf(v.w);
    reinterpret_cast<ushort4*>(out)[i] = o;
  }
}

__global__ void k_cvt_w(const float* __restrict__ W, unsigned short* __restrict__ Wt) {
  int i = blockIdx.x * blockDim.x + threadIdx.x;
  if (i < DOUT * DIN) {
    int c = i / DIN, k = i % DIN;
    Wt[i] = f2bf(W[k * DOUT + col_perm12(c)]);
  }
}

__global__ void k_hist(const int* __restrict__ idx1, int* __restrict__ icounts) {
  int stride = gridDim.x * blockDim.x;
  for (int e = blockIdx.x * blockDim.x + threadIdx.x; e < N_EDGES; e += stride)
    atomicAdd(&icounts[idx1[e]], 1);
}

// ---- 3-phase multi-block exclusive scan of icounts[50000] -> offsets ----
#define SCAN_B 512
#define SCAN_NB 98
__global__ void k_scanA(const int* __restrict__ ic, int* __restrict__ off,
                        int* __restrict__ bsum) {
  __shared__ int tmp[SCAN_B];
  int tid = threadIdx.x, i = blockIdx.x * SCAN_B + tid;
  int v = (i < N_NODES) ? ic[i] : 0;
  tmp[tid] = v;
  __syncthreads();
  for (int o = 1; o < SCAN_B; o <<= 1) {
    int t = (tid >= o) ? tmp[tid - o] : 0;
    __syncthreads();
    tmp[tid] += t;
    __syncthreads();
  }
  if (i < N_NODES) off[i] = tmp[tid] - v;
  if (tid == SCAN_B - 1) bsum[blockIdx.x] = tmp[tid];
}
__global__ void k_scanB(const int* __restrict__ bsum, int* __restrict__ boff) {
  __shared__ int tmp[128];
  int tid = threadIdx.x;
  int v = (tid < SCAN_NB) ? bsum[tid] : 0;
  tmp[tid] = v;
  __syncthreads();
  for (int o = 1; o < 128; o <<= 1) {
    int t = (tid >= o) ? tmp[tid - o] : 0;
    __syncthreads();
    tmp[tid] += t;
    __syncthreads();
  }
  if (tid < SCAN_NB) boff[tid] = tmp[tid] - v;
}
__global__ void k_scanC(int* __restrict__ off, const int* __restrict__ boff) {
  int i = blockIdx.x * SCAN_B + threadIdx.x;
  if (i < N_NODES) off[i] += boff[blockIdx.x];
}

// scatter edge ids into sorted-by-idx1 order; also pre-gather idx2
__global__ void k_perm(const int* __restrict__ idx1, const int* __restrict__ idx2,
                       const int* __restrict__ offsets, int* __restrict__ cursor,
                       int* __restrict__ perm, int* __restrict__ i1s,
                       int* __restrict__ i2s) {
  int stride = gridDim.x * blockDim.x;
  for (int e = blockIdx.x * blockDim.x + threadIdx.x; e < N_EDGES; e += stride) {
    int n = idx1[e];
    int p = offsets[n] + atomicAdd(&cursor[n], 1);
    perm[p] = e;
    i1s[p] = n;
    i2s[p] = idx2[e];
  }
}

// ---------------- shared GEMM machinery (12 waves x 16 cols) ----------------
// 768 threads; 64 rows/tile; W(bf16) 32 VGPR/wave; A double-buffered 2x32KB;
// one barrier/tile; reg-prefetch sv[3]. 2 blocks/CU = 24 waves (2x R13 TLP).

#define GEMM_PROLOGUE()                                                        \
  const int tid = threadIdx.x;                                                 \
  const int lane = tid & 63;                                                   \
  const int w = tid >> 6;                                                      \
  const int lm = lane & 15;                                                    \
  const int hi = lane >> 4;                                                    \
  bf16x8 breg[8];                                                              \
  _Pragma("unroll") for (int ks = 0; ks < 8; ++ks)                             \
      breg[ks] = *reinterpret_cast<const bf16x8*>(                             \
          Wt + (size_t)(w * 16 + lm) * DIN + ks * 32 + hi * 8);                \
  uint4 sv[3];

#define LOAD_TILE(T)                                                           \
  {                                                                            \
    const int e0_ = (T) * 64;                                                  \
    _Pragma("unroll") for (int k = 0; k < 3; ++k) {                            \
      int i = tid + k * 768;                                                   \
      if (i < 2048) {                                                          \
        int r = i >> 5, cs = i & 31;                                           \
        int es = e0_ + rperm_(r);                                              \
        int i1 = i1s[es];                                                      \
        int i2 = i2s[es];                                                      \
        int ep = perm[es];                                                     \
        const unsigned short* s0 = nb + (size_t)i1 * NF + cs * 8;              \
        const unsigned short* s1 = nb + (size_t)i2 * NF + (cs - 12) * 8;       \
        const unsigned short* s2 = eb + (size_t)ep * FE + (cs - 24) * 8;       \
        const unsigned short* src = cs < 12 ? s0 : (cs < 24 ? s1 : s2);        \
        sv[k] = *reinterpret_cast<const uint4*>(src);                          \
      }                                                                        \
    }                                                                          \
  }

#define WRITE_TILE(P)                                                          \
  _Pragma("unroll") for (int k = 0; k < 3; ++k) {                              \
    int i = tid + k * 768;                                                     \
    if (i < 2048) {                                                            \
      int r = i >> 5, cs = i & 31;                                             \
      *reinterpret_cast<uint4*>(&As[P][r * 256 + ((cs ^ (r & 7)) * 8)]) = sv[k]; \
    }                                                                          \
  }

#define COMPUTE_TILE(P)                                                        \
  _Pragma("unroll") for (int ks = 0; ks < 8; ++ks) {                           \
    bf16x8 a[4];                                                               \
    _Pragma("unroll") for (int rf = 0; rf < 4; ++rf) {                         \
      int row = rf * 16 + lm;                                                  \
      int slot = (ks * 4 + hi) ^ (lm & 7);                                     \
      a[rf] = *reinterpret_cast<const bf16x8*>(&As[P][row * 256 + slot * 8]);  \
    }                                                                          \
    _Pragma("unroll") for (int rf = 0; rf < 4; ++rf)                           \
      acc[rf] = __builtin_amdgcn_mfma_f32_16x16x32_bf16(a[rf], breg[ks],       \
                                                        acc[rf], 0, 0, 0);     \
  }

// PASS 0: column stats of y = XW over stride-4 tile subsample (200k edges)
__global__ __launch_bounds__(768, 6) void k_gstats(
    const unsigned short* __restrict__ nb, const unsigned short* __restrict__ eb,
    const unsigned short* __restrict__ Wt, const int* __restrict__ perm,
    const int* __restrict__ i1s, const int* __restrict__ i2s,
    float* __restrict__ colsum, float* __restrict__ colsumsq) {
  __shared__ unsigned short As[2][64 * 256];  // 64 KB
  GEMM_PROLOGUE();
  float s1a = 0.f, s2a = 0.f;

  int s = blockIdx.x;
  int p = 0;
  if (s < NSAMP) LOAD_TILE(s * SSTRIDE);
  for (; s < NSAMP; s += gridDim.x) {
    WRITE_TILE(p);
    __syncthreads();
    int ns = s + gridDim.x;
    if (ns < NSAMP) LOAD_TILE(ns * SSTRIDE);

    f32x4 acc[4];
#pragma unroll
    for (int rf = 0; rf < 4; ++rf) acc[rf] = (f32x4)(0.f);
    COMPUTE_TILE(p);

#pragma unroll
    for (int rf = 0; rf < 4; ++rf)
#pragma unroll
      for (int j = 0; j < 4; ++j) {
        float y = acc[rf][j];
        s1a += y;
        s2a += y * y;
      }
    p ^= 1;
  }

  {
    float s1 = s1a, s2 = s2a;
    s1 += __shfl_xor(s1, 16); s2 += __shfl_xor(s2, 16);
    s1 += __shfl_xor(s1, 32); s2 += __shfl_xor(s2, 32);
    if (lane < 16) {
      atomicAdd(&colsum[w * 16 + lane], s1);
      atomicAdd(&colsumsq[w * 16 + lane], s2);
    }
  }
}

// PASS 1: zhat = y*a1 + b1f; msg = sigmoid(gate)*softplus(conv) via
// cross-lane pair (shfl_xor 8); in-register segmented scatter (lm<8 lanes)
__global__ __launch_bounds__(768, 6) void k_gmsg2(
    const unsigned short* __restrict__ nb, const unsigned short* __restrict__ eb,
    const unsigned short* __restrict__ Wt, const int* __restrict__ perm,
    const int* __restrict__ i1s, const int* __restrict__ i2s,
    const float* __restrict__ a1, const float* __restrict__ b1f,
    float* __restrict__ sums) {
  __shared__ unsigned short As[2][64 * 256];  // 64 KB
  GEMM_PROLOGUE();
  const float c0 = a1[w * 16 + lm];
  const float c1 = b1f[w * 16 + lm];
  const int mcol = w * 8 + (lm & 7);  // orig gate/msg column

  int tile = blockIdx.x;
  int p = 0;
  if (tile < NTILES) LOAD_TILE(tile);
  for (; tile < NTILES; tile += gridDim.x) {
    const int e0 = tile * 64;
    WRITE_TILE(p);
    __syncthreads();
    int nt = tile + gridDim.x;
    if (nt < NTILES) LOAD_TILE(nt);

    f32x4 acc[4];
#pragma unroll
    for (int rf = 0; rf < 4; ++rf) acc[rf] = (f32x4)(0.f);
    COMPUTE_TILE(p);

    // node ids for this thread's 16 consecutive sorted edges (64B-aligned)
    const int4* ip = reinterpret_cast<const int4*>(&i1s[e0 + hi * 16]);
    int4 n0 = ip[0], n1 = ip[1], n2 = ip[2], n3 = ip[3];
    int nidv[16] = {n0.x, n0.y, n0.z, n0.w, n1.x, n1.y, n1.z, n1.w,
                    n2.x, n2.y, n2.z, n2.w, n3.x, n3.y, n3.z, n3.w};

    float run = 0.f;
    int curn = nidv[0];
#pragma unroll
    for (int rf = 0; rf < 4; ++rf)
#pragma unroll
      for (int j = 0; j < 4; ++j) {
        int k = rf * 4 + j;
        float z = acc[rf][j] * c0 + c1;
        float v = (lm < 8) ? sigmoidf_(z) : softplusf_(z);
        float pp = __shfl_xor(v, 8);
        run += v * pp;
        int nxt = (k < 15) ? nidv[(k + 1) & 15] : -1;
        if (nxt != curn) {
          if (lm < 8) atomicAdd(&sums[(size_t)curn * NF + mcol], run);
          run = 0.f;
          curn = nxt;
        }
      }
    p ^= 1;
  }
}

// ---------------- BN affine computation ----------------
// stats from the 200k-edge subsample (unbiased estimators of batch stats)
__global__ void k_bn1(const float* __restrict__ colsum, const float* __restrict__ colsumsq,
                      const float* __restrict__ gamma1, const float* __restrict__ beta1,
                      float* __restrict__ a1, float* __restrict__ b1f) {
  int c = threadIdx.x;  // 192, our col space
  int o = col_perm12(c);
  const float inv_n = 1.f / (float)(NSAMP * 64);
  float my = colsum[c] * inv_n;
  float v = colsumsq[c] * inv_n - my * my;
  float a = gamma1[o] * rsqrtf(v + BN_EPS);
  a1[c] = a;
  b1f[c] = beta1[o] - my * a;  // bias cancels against batch mean
}

__global__ void k_nodestats(const float* __restrict__ sums, const int* __restrict__ icounts,
                            float* __restrict__ colsum2, float* __restrict__ colsumsq2) {
  __shared__ float sh[2][2][96];
  int t = threadIdx.x;  // 192
  int c = t % 96, sub = t / 96;
  float s1 = 0.f, s2 = 0.f;
  int n0 = blockIdx.x * 256;
  for (int r = sub; r < 256; r += 2) {
    int n = n0 + r;
    if (n < N_NODES) {
      float v = sums[(size_t)n * NF + c] / fmaxf((float)icounts[n], 1.f);
      s1 += v; s2 += v * v;
    }
  }
  sh[0][sub][c] = s1; sh[1][sub][c] = s2;
  __syncthreads();
  if (sub == 0) {
    atomicAdd(&colsum2[c], s1 + sh[0][1][c]);
    atomicAdd(&colsumsq2[c], s2 + sh[1][1][c]);
  }
}

__global__ void k_bn2(const float* __restrict__ colsum2, const float* __restrict__ colsumsq2,
                      const float* __restrict__ gamma2, const float* __restrict__ beta2,
                      float* __restrict__ a2, float* __restrict__ b2f) {
  int c = threadIdx.x;
  if (c < 96) {
    float m = colsum2[c] * (1.f / N_NODES);
    float v = colsumsq2[c] * (1.f / N_NODES) - m * m;
    float a = gamma2[c] * rsqrtf(v + BN_EPS);
    a2[c] = a;
    b2f[c] = beta2[c] - m * a;
  }
}

__global__ void k_final(const float* __restrict__ node, const float* __restrict__ sums,
                        const int* __restrict__ icounts, const float* __restrict__ a2,
                        const float* __restrict__ b2f, float* __restrict__ out) {
  int stride = gridDim.x * blockDim.x;
  for (int i = blockIdx.x * blockDim.x + threadIdx.x; i < N_NODES * NF / 4; i += stride) {
    int n = i / 24, c4 = (i % 24) * 4;
    float inv = 1.f / fmaxf((float)icounts[n], 1.f);
    float4 s = reinterpret_cast<const float4*>(sums)[i];
    float4 nf = reinterpret_cast<const float4*>(node)[i];
    float4 o;
    o.x = softplusf_(nf.x + s.x * inv * a2[c4 + 0] + b2f[c4 + 0]);
    o.y = softplusf_(nf.y + s.y * inv * a2[c4 + 1] + b2f[c4 + 1]);
    o.z = softplusf_(nf.z + s.z * inv * a2[c4 + 2] + b2f[c4 + 2]);
    o.w = softplusf_(nf.w + s.w * inv * a2[c4 + 3] + b2f[c4 + 3]);
    reinterpret_cast<float4*>(out)[i] = o;
  }
}

extern "C" void kernel_launch(void* const* d_in, const int* in_sizes, int n_in,
                              void* d_out, int out_size, void* d_ws, size_t ws_size,
                              hipStream_t stream) {
  const float* node = (const float*)d_in[0];
  const float* edge = (const float*)d_in[1];
  const float* W = (const float*)d_in[2];
  const float* gamma1 = (const float*)d_in[4];
  const float* beta1 = (const float*)d_in[5];
  const float* gamma2 = (const float*)d_in[6];
  const float* beta2 = (const float*)d_in[7];
  const int* idx1 = (const int*)d_in[8];
  const int* idx2 = (const int*)d_in[9];
  float* out = (float*)d_out;

  char* ws = (char*)d_ws;
  unsigned short* nb = (unsigned short*)(ws);               //   9,600,000
  unsigned short* eb = (unsigned short*)(ws + 9600000);     // 102,400,000 (orig order)
  unsigned short* Wt = (unsigned short*)(ws + 112000000);   //      98,304
  float* sums = (float*)(ws + 112098304);                   //  19,200,000
  float* stats = (float*)(ws + 131298304);                  //       8,192
  int* icounts = (int*)(ws + 131306496);                    //     200,000
  int* perm = (int*)(ws + 131506496);                       //   3,200,000
  int* i1s = (int*)(ws + 134706496);                        //   3,200,000
  int* i2s = (int*)(ws + 137906496);                        //   3,200,000
  // total 141,106,496 bytes

  // overlay at head of sums (used only before k_gmsg2, re-zeroed after)
  int* offsets = (int*)(ws + 112098304);        // 50000 ints
  int* cursor = offsets + 50048;                // 50000 ints

  float* colsum1 = stats;          // 192
  float* colsumsq1 = stats + 192;  // 192
  float* colsum2 = stats + 384;    // 96
  float* colsumsq2 = stats + 480;  // 96
  float* a1 = stats + 576;         // 192
  float* b1f = stats + 768;        // 192
  float* a2 = stats + 960;         // 96
  float* b2f = stats + 1056;       // 96
  int* bsum = (int*)(ws + 131303424);  // 128 ints
  int* boff = (int*)(ws + 131303936);  // 128 ints

  // zero sums (incl. offsets/cursor overlay) + stats + icounts
  (void)hipMemsetAsync(ws + 112098304, 0, 19200000 + 8192 + 200000, stream);

  k_cvt<<<2048, 256, 0, stream>>>(node, nb, N_NODES * NF / 4);
  k_cvt<<<2048, 256, 0, stream>>>(edge, eb, N_EDGES * FE / 4);
  k_cvt_w<<<DOUT * DIN / 256, 256, 0, stream>>>(W, Wt);
  k_hist<<<1024, 256, 0, stream>>>(idx1, icounts);
  k_scanA<<<SCAN_NB, SCAN_B, 0, stream>>>(icounts, offsets, bsum);
  k_scanB<<<1, 128, 0, stream>>>(bsum, boff);
  k_scanC<<<SCAN_NB, SCAN_B, 0, stream>>>(offsets, boff);
  k_perm<<<1024, 256, 0, stream>>>(idx1, idx2, offsets, cursor, perm, i1s, i2s);

  k_gstats<<<512, 768, 0, stream>>>(nb, eb, Wt, perm, i1s, i2s, colsum1, colsumsq1);
  k_bn1<<<1, 192, 0, stream>>>(colsum1, colsumsq1, gamma1, beta1, a1, b1f);

  // re-zero the overlay region before atomic accumulation into sums
  (void)hipMemsetAsync(ws + 112098304, 0, 524288, stream);

  k_gmsg2<<<512, 768, 0, stream>>>(nb, eb, Wt, perm, i1s, i2s, a1, b1f, sums);

  k_nodestats<<<(N_NODES + 255) / 256, 192, 0, stream>>>(sums, icounts, colsum2, colsumsq2);
  k_bn2<<<1, 128, 0, stream>>>(colsum2, colsumsq2, gamma2, beta2, a2, b2f);
  k_final<<<2048, 256, 0, stream>>>(node, sums, icounts, a2, b2f, out);
}

// Round 16
// 688.856 us; speedup vs baseline: 1.3964x; 1.0932x over previous
//
#include <hip/hip_runtime.h>
#include <stddef.h>
#include <stdint.h>

#define N_NODES 50000
#define N_EDGES 800000
#define NF 96
#define FE 64
#define DIN 256
#define DOUT 192
#define BN_EPS 1e-5f
#define NTILES (N_EDGES / 64)
#define SSTRIDE 4                  // stats subsample: every 4th tile
#define NSAMP (NTILES / SSTRIDE)   // 3125 tiles = 200000 edges

typedef float f32x4 __attribute__((ext_vector_type(4)));
typedef short bf16x8 __attribute__((ext_vector_type(8)));

__device__ __forceinline__ unsigned short f2bf(float f) {
  unsigned int u = __float_as_uint(f);
  return (unsigned short)((u + 0x7fffu + ((u >> 16) & 1u)) >> 16);
}
__device__ __forceinline__ float sigmoidf_(float x) {
  return 1.f / (1.f + __expf(-x));
}
__device__ __forceinline__ float softplusf_(float x) {
  float t = exp2f(-fabsf(x) * 1.44269504f);
  return fmaxf(x, 0.f) + 0.69314718f * log2f(1.f + t);
}

// row permutation: A-row r holds sorted-edge e0 + rperm_(r); swaps rf<->hi so a
// thread's 16 C-fragment values are 16 CONSECUTIVE sorted edges.
__device__ __forceinline__ int rperm_(int r) {
  return ((r >> 2) & 3) * 16 + (r >> 4) * 4 + (r & 3);
}

// 12-wave col mapping: our col c' = w*16 + l (w in [0,12), l in [0,16)).
// l<8 -> gate col w*8+l ; l>=8 -> conv col 96 + w*8 + (l-8).
// => lane lm and lane lm+8 of wave w hold a gate/conv PAIR (shfl_xor(8)).
__device__ __forceinline__ int col_perm12(int c) {
  int w = c >> 4, l = c & 15;
  return (l < 8) ? (w * 8 + l) : (96 + w * 8 + l - 8);
}

// ---------------- conversion / sort kernels ----------------
__global__ void k_cvt(const float* __restrict__ in, unsigned short* __restrict__ out, int n4) {
  int stride = gridDim.x * blockDim.x;
  for (int i = blockIdx.x * blockDim.x + threadIdx.x; i < n4; i += stride) {
    float4 v = reinterpret_cast<const float4*>(in)[i];
    ushort4 o;
    o.x = f2bf(v.x); o.y = f2bf(v.y); o.z = f2bf(v.z); o.w = f2bf(v.w);
    reinterpret_cast<ushort4*>(out)[i] = o;
  }
}

__global__ void k_cvt_w(const float* __restrict__ W, unsigned short* __restrict__ Wt) {
  int i = blockIdx.x * blockDim.x + threadIdx.x;
  if (i < DOUT * DIN) {
    int c = i / DIN, k = i % DIN;
    Wt[i] = f2bf(W[k * DOUT + col_perm12(c)]);
  }
}

__global__ void k_hist(const int* __restrict__ idx1, int* __restrict__ icounts) {
  int stride = gridDim.x * blockDim.x;
  for (int e = blockIdx.x * blockDim.x + threadIdx.x; e < N_EDGES; e += stride)
    atomicAdd(&icounts[idx1[e]], 1);
}

// ---- 3-phase multi-block exclusive scan of icounts[50000] -> offsets ----
#define SCAN_B 512
#define SCAN_NB 98
__global__ void k_scanA(const int* __restrict__ ic, int* __restrict__ off,
                        int* __restrict__ bsum) {
  __shared__ int tmp[SCAN_B];
  int tid = threadIdx.x, i = blockIdx.x * SCAN_B + tid;
  int v = (i < N_NODES) ? ic[i] : 0;
  tmp[tid] = v;
  __syncthreads();
  for (int o = 1; o < SCAN_B; o <<= 1) {
    int t = (tid >= o) ? tmp[tid - o] : 0;
    __syncthreads();
    tmp[tid] += t;
    __syncthreads();
  }
  if (i < N_NODES) off[i] = tmp[tid] - v;
  if (tid == SCAN_B - 1) bsum[blockIdx.x] = tmp[tid];
}
__global__ void k_scanB(const int* __restrict__ bsum, int* __restrict__ boff) {
  __shared__ int tmp[128];
  int tid = threadIdx.x;
  int v = (tid < SCAN_NB) ? bsum[tid] : 0;
  tmp[tid] = v;
  __syncthreads();
  for (int o = 1; o < 128; o <<= 1) {
    int t = (tid >= o) ? tmp[tid - o] : 0;
    __syncthreads();
    tmp[tid] += t;
    __syncthreads();
  }
  if (tid < SCAN_NB) boff[tid] = tmp[tid] - v;
}
__global__ void k_scanC(int* __restrict__ off, const int* __restrict__ boff) {
  int i = blockIdx.x * SCAN_B + threadIdx.x;
  if (i < N_NODES) off[i] += boff[blockIdx.x];
}

// scatter edge ids into sorted-by-idx1 order; also pre-gather idx2
__global__ void k_perm(const int* __restrict__ idx1, const int* __restrict__ idx2,
                       const int* __restrict__ offsets, int* __restrict__ cursor,
                       int* __restrict__ perm, int* __restrict__ i1s,
                       int* __restrict__ i2s) {
  int stride = gridDim.x * blockDim.x;
  for (int e = blockIdx.x * blockDim.x + threadIdx.x; e < N_EDGES; e += stride) {
    int n = idx1[e];
    int p = offsets[n] + atomicAdd(&cursor[n], 1);
    perm[p] = e;
    i1s[p] = n;
    i2s[p] = idx2[e];
  }
}

// ---------------- shared GEMM machinery (12 waves x 16 cols) ----------------
// 768 threads; 64 rows/tile; W(bf16) 32 VGPR/wave; A double-buffered 2x32KB;
// one barrier/tile; reg-prefetch sv[3]. Register budget target: <=85 VGPR
// (512/6 waves-per-EU) -> 2 blocks/CU = 24 waves. a[] processed in PAIRS and
// nid kept in LDS to stay under the cap (R15 spilled at ~95).

#define GEMM_PROLOGUE()                                                        \
  const int tid = threadIdx.x;                                                 \
  const int lane = tid & 63;                                                   \
  const int w = tid >> 6;                                                      \
  const int lm = lane & 15;                                                    \
  const int hi = lane >> 4;                                                    \
  bf16x8 breg[8];                                                              \
  _Pragma("unroll") for (int ks = 0; ks < 8; ++ks)                             \
      breg[ks] = *reinterpret_cast<const bf16x8*>(                             \
          Wt + (size_t)(w * 16 + lm) * DIN + ks * 32 + hi * 8);                \
  uint4 sv[3];

#define LOAD_TILE(T)                                                           \
  {                                                                            \
    const int e0_ = (T) * 64;                                                  \
    _Pragma("unroll") for (int k = 0; k < 3; ++k) {                            \
      int i = tid + k * 768;                                                   \
      if (i < 2048) {                                                          \
        int r = i >> 5, cs = i & 31;                                           \
        int es = e0_ + rperm_(r);                                              \
        int i1 = i1s[es];                                                      \
        int i2 = i2s[es];                                                      \
        int ep = perm[es];                                                     \
        const unsigned short* s0 = nb + (size_t)i1 * NF + cs * 8;              \
        const unsigned short* s1 = nb + (size_t)i2 * NF + (cs - 12) * 8;       \
        const unsigned short* s2 = eb + (size_t)ep * FE + (cs - 24) * 8;       \
        const unsigned short* src = cs < 12 ? s0 : (cs < 24 ? s1 : s2);        \
        sv[k] = *reinterpret_cast<const uint4*>(src);                          \
      }                                                                        \
    }                                                                          \
  }

#define WRITE_TILE(P)                                                          \
  _Pragma("unroll") for (int k = 0; k < 3; ++k) {                              \
    int i = tid + k * 768;                                                     \
    if (i < 2048) {                                                            \
      int r = i >> 5, cs = i & 31;                                             \
      *reinterpret_cast<uint4*>(&As[P][r * 256 + ((cs ^ (r & 7)) * 8)]) = sv[k]; \
    }                                                                          \
  }

// rows processed in PAIRS (a0,a1) to halve live A-fragment registers
#define COMPUTE_TILE(P)                                                        \
  _Pragma("unroll") for (int ks = 0; ks < 8; ++ks) {                           \
    int slot = (ks * 4 + hi) ^ (lm & 7);                                       \
    {                                                                          \
      bf16x8 a0 = *reinterpret_cast<const bf16x8*>(                            \
          &As[P][(0 * 16 + lm) * 256 + slot * 8]);                             \
      bf16x8 a1 = *reinterpret_cast<const bf16x8*>(                            \
          &As[P][(1 * 16 + lm) * 256 + slot * 8]);                             \
      acc[0] = __builtin_amdgcn_mfma_f32_16x16x32_bf16(a0, breg[ks], acc[0], 0, 0, 0); \
      acc[1] = __builtin_amdgcn_mfma_f32_16x16x32_bf16(a1, breg[ks], acc[1], 0, 0, 0); \
    }                                                                          \
    {                                                                          \
      bf16x8 a0 = *reinterpret_cast<const bf16x8*>(                            \
          &As[P][(2 * 16 + lm) * 256 + slot * 8]);                             \
      bf16x8 a1 = *reinterpret_cast<const bf16x8*>(                            \
          &As[P][(3 * 16 + lm) * 256 + slot * 8]);                             \
      acc[2] = __builtin_amdgcn_mfma_f32_16x16x32_bf16(a0, breg[ks], acc[2], 0, 0, 0); \
      acc[3] = __builtin_amdgcn_mfma_f32_16x16x32_bf16(a1, breg[ks], acc[3], 0, 0, 0); \
    }                                                                          \
  }

// PASS 0: column stats of y = XW over stride-4 tile subsample (200k edges)
__global__ __launch_bounds__(768, 6) void k_gstats(
    const unsigned short* __restrict__ nb, const unsigned short* __restrict__ eb,
    const unsigned short* __restrict__ Wt, const int* __restrict__ perm,
    const int* __restrict__ i1s, const int* __restrict__ i2s,
    float* __restrict__ colsum, float* __restrict__ colsumsq) {
  __shared__ unsigned short As[2][64 * 256];  // 64 KB
  GEMM_PROLOGUE();
  float s1a = 0.f, s2a = 0.f;

  int s = blockIdx.x;
  int p = 0;
  if (s < NSAMP) LOAD_TILE(s * SSTRIDE);
  for (; s < NSAMP; s += gridDim.x) {
    WRITE_TILE(p);
    __syncthreads();
    int ns = s + gridDim.x;
    if (ns < NSAMP) LOAD_TILE(ns * SSTRIDE);

    f32x4 acc[4];
#pragma unroll
    for (int rf = 0; rf < 4; ++rf) acc[rf] = (f32x4)(0.f);
    COMPUTE_TILE(p);

#pragma unroll
    for (int rf = 0; rf < 4; ++rf)
#pragma unroll
      for (int j = 0; j < 4; ++j) {
        float y = acc[rf][j];
        s1a += y;
        s2a += y * y;
      }
    p ^= 1;
  }

  {
    float s1 = s1a, s2 = s2a;
    s1 += __shfl_xor(s1, 16); s2 += __shfl_xor(s2, 16);
    s1 += __shfl_xor(s1, 32); s2 += __shfl_xor(s2, 32);
    if (lane < 16) {
      atomicAdd(&colsum[w * 16 + lane], s1);
      atomicAdd(&colsumsq[w * 16 + lane], s2);
    }
  }
}

// PASS 1: zhat = y*a1 + b1f; msg = sigmoid(gate)*softplus(conv) via
// cross-lane pair (shfl_xor 8); in-register segmented scatter (lm<8 lanes);
// node ids read from double-buffered LDS (saves 16 VGPR vs register copy)
__global__ __launch_bounds__(768, 6) void k_gmsg2(
    const unsigned short* __restrict__ nb, const unsigned short* __restrict__ eb,
    const unsigned short* __restrict__ Wt, const int* __restrict__ perm,
    const int* __restrict__ i1s, const int* __restrict__ i2s,
    const float* __restrict__ a1, const float* __restrict__ b1f,
    float* __restrict__ sums) {
  __shared__ unsigned short As[2][64 * 256];  // 64 KB
  __shared__ int nidl[2][64];                 // 512 B
  GEMM_PROLOGUE();
  const float c0 = a1[w * 16 + lm];
  const float c1 = b1f[w * 16 + lm];
  const int mcol = w * 8 + (lm & 7);  // orig gate/msg column

  int tile = blockIdx.x;
  int p = 0;
  if (tile < NTILES) LOAD_TILE(tile);
  for (; tile < NTILES; tile += gridDim.x) {
    const int e0 = tile * 64;
    WRITE_TILE(p);
    if (tid < 64) nidl[p][tid] = i1s[e0 + tid];
    __syncthreads();
    int nt = tile + gridDim.x;
    if (nt < NTILES) LOAD_TILE(nt);

    f32x4 acc[4];
#pragma unroll
    for (int rf = 0; rf < 4; ++rf) acc[rf] = (f32x4)(0.f);
    COMPUTE_TILE(p);

    float run = 0.f;
    int curn = nidl[p][hi * 16];
#pragma unroll
    for (int rf = 0; rf < 4; ++rf)
#pragma unroll
      for (int j = 0; j < 4; ++j) {
        int k = rf * 4 + j;
        float z = acc[rf][j] * c0 + c1;
        float v = (lm < 8) ? sigmoidf_(z) : softplusf_(z);
        float pp = __shfl_xor(v, 8);
        run += v * pp;
        int nxt = (k < 15) ? nidl[p][hi * 16 + k + 1] : -1;
        if (nxt != curn) {
          if (lm < 8) atomicAdd(&sums[(size_t)curn * NF + mcol], run);
          run = 0.f;
          curn = nxt;
        }
      }
    p ^= 1;
  }
}

// ---------------- BN affine computation ----------------
// stats from the 200k-edge subsample (unbiased estimators of batch stats)
__global__ void k_bn1(const float* __restrict__ colsum, const float* __restrict__ colsumsq,
                      const float* __restrict__ gamma1, const float* __restrict__ beta1,
                      float* __restrict__ a1, float* __restrict__ b1f) {
  int c = threadIdx.x;  // 192, our col space
  int o = col_perm12(c);
  const float inv_n = 1.f / (float)(NSAMP * 64);
  float my = colsum[c] * inv_n;
  float v = colsumsq[c] * inv_n - my * my;
  float a = gamma1[o] * rsqrtf(v + BN_EPS);
  a1[c] = a;
  b1f[c] = beta1[o] - my * a;  // bias cancels against batch mean
}

__global__ void k_nodestats(const float* __restrict__ sums, const int* __restrict__ icounts,
                            float* __restrict__ colsum2, float* __restrict__ colsumsq2) {
  __shared__ float sh[2][2][96];
  int t = threadIdx.x;  // 192
  int c = t % 96, sub = t / 96;
  float s1 = 0.f, s2 = 0.f;
  int n0 = blockIdx.x * 256;
  for (int r = sub; r < 256; r += 2) {
    int n = n0 + r;
    if (n < N_NODES) {
      float v = sums[(size_t)n * NF + c] / fmaxf((float)icounts[n], 1.f);
      s1 += v; s2 += v * v;
    }
  }
  sh[0][sub][c] = s1; sh[1][sub][c] = s2;
  __syncthreads();
  if (sub == 0) {
    atomicAdd(&colsum2[c], s1 + sh[0][1][c]);
    atomicAdd(&colsumsq2[c], s2 + sh[1][1][c]);
  }
}

__global__ void k_bn2(const float* __restrict__ colsum2, const float* __restrict__ colsumsq2,
                      const float* __restrict__ gamma2, const float* __restrict__ beta2,
                      float* __restrict__ a2, float* __restrict__ b2f) {
  int c = threadIdx.x;
  if (c < 96) {
    float m = colsum2[c] * (1.f / N_NODES);
    float v = colsumsq2[c] * (1.f / N_NODES) - m * m;
    float a = gamma2[c] * rsqrtf(v + BN_EPS);
    a2[c] = a;
    b2f[c] = beta2[c] - m * a;
  }
}

__global__ void k_final(const float* __restrict__ node, const float* __restrict__ sums,
                        const int* __restrict__ icounts, const float* __restrict__ a2,
                        const float* __restrict__ b2f, float* __restrict__ out) {
  int stride = gridDim.x * blockDim.x;
  for (int i = blockIdx.x * blockDim.x + threadIdx.x; i < N_NODES * NF / 4; i += stride) {
    int n = i / 24, c4 = (i % 24) * 4;
    float inv = 1.f / fmaxf((float)icounts[n], 1.f);
    float4 s = reinterpret_cast<const float4*>(sums)[i];
    float4 nf = reinterpret_cast<const float4*>(node)[i];
    float4 o;
    o.x = softplusf_(nf.x + s.x * inv * a2[c4 + 0] + b2f[c4 + 0]);
    o.y = softplusf_(nf.y + s.y * inv * a2[c4 + 1] + b2f[c4 + 1]);
    o.z = softplusf_(nf.z + s.z * inv * a2[c4 + 2] + b2f[c4 + 2]);
    o.w = softplusf_(nf.w + s.w * inv * a2[c4 + 3] + b2f[c4 + 3]);
    reinterpret_cast<float4*>(out)[i] = o;
  }
}

extern "C" void kernel_launch(void* const* d_in, const int* in_sizes, int n_in,
                              void* d_out, int out_size, void* d_ws, size_t ws_size,
                              hipStream_t stream) {
  const float* node = (const float*)d_in[0];
  const float* edge = (const float*)d_in[1];
  const float* W = (const float*)d_in[2];
  const float* gamma1 = (const float*)d_in[4];
  const float* beta1 = (const float*)d_in[5];
  const float* gamma2 = (const float*)d_in[6];
  const float* beta2 = (const float*)d_in[7];
  const int* idx1 = (const int*)d_in[8];
  const int* idx2 = (const int*)d_in[9];
  float* out = (float*)d_out;

  char* ws = (char*)d_ws;
  unsigned short* nb = (unsigned short*)(ws);               //   9,600,000
  unsigned short* eb = (unsigned short*)(ws + 9600000);     // 102,400,000 (orig order)
  unsigned short* Wt = (unsigned short*)(ws + 112000000);   //      98,304
  float* sums = (float*)(ws + 112098304);                   //  19,200,000
  float* stats = (float*)(ws + 131298304);                  //       8,192
  int* icounts = (int*)(ws + 131306496);                    //     200,000
  int* perm = (int*)(ws + 131506496);                       //   3,200,000
  int* i1s = (int*)(ws + 134706496);                        //   3,200,000
  int* i2s = (int*)(ws + 137906496);                        //   3,200,000
  // total 141,106,496 bytes

  // overlay at head of sums (used only before k_gmsg2, re-zeroed after)
  int* offsets = (int*)(ws + 112098304);        // 50000 ints
  int* cursor = offsets + 50048;                // 50000 ints

  float* colsum1 = stats;          // 192
  float* colsumsq1 = stats + 192;  // 192
  float* colsum2 = stats + 384;    // 96
  float* colsumsq2 = stats + 480;  // 96
  float* a1 = stats + 576;         // 192
  float* b1f = stats + 768;        // 192
  float* a2 = stats + 960;         // 96
  float* b2f = stats + 1056;       // 96
  int* bsum = (int*)(ws + 131303424);  // 128 ints
  int* boff = (int*)(ws + 131303936);  // 128 ints

  // zero sums (incl. offsets/cursor overlay) + stats + icounts
  (void)hipMemsetAsync(ws + 112098304, 0, 19200000 + 8192 + 200000, stream);

  k_cvt<<<2048, 256, 0, stream>>>(node, nb, N_NODES * NF / 4);
  k_cvt<<<2048, 256, 0, stream>>>(edge, eb, N_EDGES * FE / 4);
  k_cvt_w<<<DOUT * DIN / 256, 256, 0, stream>>>(W, Wt);
  k_hist<<<1024, 256, 0, stream>>>(idx1, icounts);
  k_scanA<<<SCAN_NB, SCAN_B, 0, stream>>>(icounts, offsets, bsum);
  k_scanB<<<1, 128, 0, stream>>>(bsum, boff);
  k_scanC<<<SCAN_NB, SCAN_B, 0, stream>>>(offsets, boff);
  k_perm<<<1024, 256, 0, stream>>>(idx1, idx2, offsets, cursor, perm, i1s, i2s);

  k_gstats<<<512, 768, 0, stream>>>(nb, eb, Wt, perm, i1s, i2s, colsum1, colsumsq1);
  k_bn1<<<1, 192, 0, stream>>>(colsum1, colsumsq1, gamma1, beta1, a1, b1f);

  // re-zero the overlay region before atomic accumulation into sums
  (void)hipMemsetAsync(ws + 112098304, 0, 524288, stream);

  k_gmsg2<<<512, 768, 0, stream>>>(nb, eb, Wt, perm, i1s, i2s, a1, b1f, sums);

  k_nodestats<<<(N_NODES + 255) / 256, 192, 0, stream>>>(sums, icounts, colsum2, colsumsq2);
  k_bn2<<<1, 128, 0, stream>>>(colsum2, colsumsq2, gamma2, beta2, a2, b2f);
  k_final<<<2048, 256, 0, stream>>>(node, sums, icounts, a2, b2f, out);
}

// Round 17
// 644.924 us; speedup vs baseline: 1.4915x; 1.0681x over previous
//
#include <hip/hip_runtime.h>
#include <stddef.h>
#include <stdint.h>

#define N_NODES 50000
#define N_EDGES 800000
#define NF 96
#define FE 64
#define DIN 256
#define DOUT 192
#define BN_EPS 1e-5f
#define NTILES (N_EDGES / 64)
#define SSTRIDE 4                  // stats subsample: every 4th tile
#define NSAMP (NTILES / SSTRIDE)   // 3125 tiles = 200000 edges

typedef float f32x4 __attribute__((ext_vector_type(4)));
typedef short bf16x8 __attribute__((ext_vector_type(8)));

__device__ __forceinline__ unsigned short f2bf(float f) {
  unsigned int u = __float_as_uint(f);
  return (unsigned short)((u + 0x7fffu + ((u >> 16) & 1u)) >> 16);
}
__device__ __forceinline__ float sigmoidf_(float x) {
  return 1.f / (1.f + __expf(-x));
}
__device__ __forceinline__ float softplusf_(float x) {
  float t = exp2f(-fabsf(x) * 1.44269504f);
  return fmaxf(x, 0.f) + 0.69314718f * log2f(1.f + t);
}

// row permutation: A-row r holds sorted-edge e0 + rperm_(r); swaps rf<->hi so a
// thread's 16 C-fragment values are 16 CONSECUTIVE sorted edges.
__device__ __forceinline__ int rperm_(int r) {
  return ((r >> 2) & 3) * 16 + (r >> 4) * 4 + (r & 3);
}

// 12-wave col mapping: our col c' = w*16 + l (w in [0,12), l in [0,16)).
// l<8 -> gate col w*8+l ; l>=8 -> conv col 96 + w*8 + (l-8).
// => lane lm and lane lm+8 of wave w hold a gate/conv PAIR (shfl_xor(8)).
__device__ __forceinline__ int col_perm12(int c) {
  int w = c >> 4, l = c & 15;
  return (l < 8) ? (w * 8 + l) : (96 + w * 8 + l - 8);
}

// ---------------- conversion / sort kernels ----------------
__global__ void k_cvt(const float* __restrict__ in, unsigned short* __restrict__ out, int n4) {
  int stride = gridDim.x * blockDim.x;
  for (int i = blockIdx.x * blockDim.x + threadIdx.x; i < n4; i += stride) {
    float4 v = reinterpret_cast<const float4*>(in)[i];
    ushort4 o;
    o.x = f2bf(v.x); o.y = f2bf(v.y); o.z = f2bf(v.z); o.w = f2bf(v.w);
    reinterpret_cast<ushort4*>(out)[i] = o;
  }
}

__global__ void k_cvt_w(const float* __restrict__ W, unsigned short* __restrict__ Wt) {
  int i = blockIdx.x * blockDim.x + threadIdx.x;
  if (i < DOUT * DIN) {
    int c = i / DIN, k = i % DIN;
    Wt[i] = f2bf(W[k * DOUT + col_perm12(c)]);
  }
}

__global__ void k_hist(const int* __restrict__ idx1, int* __restrict__ icounts) {
  int stride = gridDim.x * blockDim.x;
  for (int e = blockIdx.x * blockDim.x + threadIdx.x; e < N_EDGES; e += stride)
    atomicAdd(&icounts[idx1[e]], 1);
}

// ---- 3-phase multi-block exclusive scan of icounts[50000] -> offsets ----
#define SCAN_B 512
#define SCAN_NB 98
__global__ void k_scanA(const int* __restrict__ ic, int* __restrict__ off,
                        int* __restrict__ bsum) {
  __shared__ int tmp[SCAN_B];
  int tid = threadIdx.x, i = blockIdx.x * SCAN_B + tid;
  int v = (i < N_NODES) ? ic[i] : 0;
  tmp[tid] = v;
  __syncthreads();
  for (int o = 1; o < SCAN_B; o <<= 1) {
    int t = (tid >= o) ? tmp[tid - o] : 0;
    __syncthreads();
    tmp[tid] += t;
    __syncthreads();
  }
  if (i < N_NODES) off[i] = tmp[tid] - v;
  if (tid == SCAN_B - 1) bsum[blockIdx.x] = tmp[tid];
}
__global__ void k_scanB(const int* __restrict__ bsum, int* __restrict__ boff) {
  __shared__ int tmp[128];
  int tid = threadIdx.x;
  int v = (tid < SCAN_NB) ? bsum[tid] : 0;
  tmp[tid] = v;
  __syncthreads();
  for (int o = 1; o < 128; o <<= 1) {
    int t = (tid >= o) ? tmp[tid - o] : 0;
    __syncthreads();
    tmp[tid] += t;
    __syncthreads();
  }
  if (tid < SCAN_NB) boff[tid] = tmp[tid] - v;
}
__global__ void k_scanC(int* __restrict__ off, const int* __restrict__ boff) {
  int i = blockIdx.x * SCAN_B + threadIdx.x;
  if (i < N_NODES) off[i] += boff[blockIdx.x];
}

// scatter edge ids into sorted-by-idx1 order; also pre-gather idx2
__global__ void k_perm(const int* __restrict__ idx1, const int* __restrict__ idx2,
                       const int* __restrict__ offsets, int* __restrict__ cursor,
                       int* __restrict__ perm, int* __restrict__ i1s,
                       int* __restrict__ i2s) {
  int stride = gridDim.x * blockDim.x;
  for (int e = blockIdx.x * blockDim.x + threadIdx.x; e < N_EDGES; e += stride) {
    int n = idx1[e];
    int p = offsets[n] + atomicAdd(&cursor[n], 1);
    perm[p] = e;
    i1s[p] = n;
    i2s[p] = idx2[e];
  }
}

// ---------------- shared GEMM machinery (12 waves x 16 cols) ----------------
// 768 threads; 64 rows/tile; A double-buffered 2x32KB; one barrier/tile;
// reg-prefetch sv[3]. W is NOT register-resident: the wave's B fragment is
// re-read from L2 (96KB Wt, L2-resident) each K-step through an asm-opaqued
// pointer, so live B = 8 VGPR. Budget ~65 VGPR < 85 cap (512/6 waves-per-EU)
// -> 2 blocks/CU = 24 waves CLEAN (R15/R16 spilled at this occupancy).

#define GEMM_PROLOGUE()                                                        \
  const int tid = threadIdx.x;                                                 \
  const int lane = tid & 63;                                                   \
  const int w = tid >> 6;                                                      \
  const int lm = lane & 15;                                                    \
  const int hi = lane >> 4;                                                    \
  const size_t wfoff = (size_t)(w * 16 + lm) * DIN + hi * 8;                   \
  uint4 sv[3];

#define LOAD_TILE(T)                                                           \
  {                                                                            \
    const int e0_ = (T) * 64;                                                  \
    _Pragma("unroll") for (int k = 0; k < 3; ++k) {                            \
      int i = tid + k * 768;                                                   \
      if (i < 2048) {                                                          \
        int r = i >> 5, cs = i & 31;                                           \
        int es = e0_ + rperm_(r);                                              \
        int i1 = i1s[es];                                                      \
        int i2 = i2s[es];                                                      \
        int ep = perm[es];                                                     \
        const unsigned short* s0 = nb + (size_t)i1 * NF + cs * 8;              \
        const unsigned short* s1 = nb + (size_t)i2 * NF + (cs - 12) * 8;       \
        const unsigned short* s2 = eb + (size_t)ep * FE + (cs - 24) * 8;       \
        const unsigned short* src = cs < 12 ? s0 : (cs < 24 ? s1 : s2);        \
        sv[k] = *reinterpret_cast<const uint4*>(src);                          \
      }                                                                        \
    }                                                                          \
  }

#define WRITE_TILE(P)                                                          \
  _Pragma("unroll") for (int k = 0; k < 3; ++k) {                              \
    int i = tid + k * 768;                                                     \
    if (i < 2048) {                                                            \
      int r = i >> 5, cs = i & 31;                                             \
      *reinterpret_cast<uint4*>(&As[P][r * 256 + ((cs ^ (r & 7)) * 8)]) = sv[k]; \
    }                                                                          \
  }

// per-K-step B reload through opaque pointer (prevents hoisting to registers);
// rows processed in PAIRS to limit live A fragments
#define COMPUTE_TILE(P)                                                        \
  {                                                                            \
    uintptr_t wp_ = (uintptr_t)Wt;                                             \
    _Pragma("unroll") for (int ks = 0; ks < 8; ++ks) {                         \
      asm volatile("" : "+s"(wp_));                                            \
      const unsigned short* Wo = (const unsigned short*)wp_;                   \
      bf16x8 bfr = *reinterpret_cast<const bf16x8*>(Wo + wfoff + ks * 32);     \
      int slot = (ks * 4 + hi) ^ (lm & 7);                                     \
      {                                                                        \
        bf16x8 a0 = *reinterpret_cast<const bf16x8*>(                          \
            &As[P][(0 * 16 + lm) * 256 + slot * 8]);                           \
        bf16x8 a1 = *reinterpret_cast<const bf16x8*>(                          \
            &As[P][(1 * 16 + lm) * 256 + slot * 8]);                           \
        acc[0] = __builtin_amdgcn_mfma_f32_16x16x32_bf16(a0, bfr, acc[0], 0, 0, 0); \
        acc[1] = __builtin_amdgcn_mfma_f32_16x16x32_bf16(a1, bfr, acc[1], 0, 0, 0); \
      }                                                                        \
      {                                                                        \
        bf16x8 a0 = *reinterpret_cast<const bf16x8*>(                          \
            &As[P][(2 * 16 + lm) * 256 + slot * 8]);                           \
        bf16x8 a1 = *reinterpret_cast<const bf16x8*>(                          \
            &As[P][(3 * 16 + lm) * 256 + slot * 8]);                           \
        acc[2] = __builtin_amdgcn_mfma_f32_16x16x32_bf16(a0, bfr, acc[2], 0, 0, 0); \
        acc[3] = __builtin_amdgcn_mfma_f32_16x16x32_bf16(a1, bfr, acc[3], 0, 0, 0); \
      }                                                                        \
    }                                                                          \
  }

// PASS 0: column stats of y = XW over stride-4 tile subsample (200k edges)
__global__ __launch_bounds__(768, 6) void k_gstats(
    const unsigned short* __restrict__ nb, const unsigned short* __restrict__ eb,
    const unsigned short* __restrict__ Wt, const int* __restrict__ perm,
    const int* __restrict__ i1s, const int* __restrict__ i2s,
    float* __restrict__ colsum, float* __restrict__ colsumsq) {
  __shared__ unsigned short As[2][64 * 256];  // 64 KB
  GEMM_PROLOGUE();
  float s1a = 0.f, s2a = 0.f;

  int s = blockIdx.x;
  int p = 0;
  if (s < NSAMP) LOAD_TILE(s * SSTRIDE);
  for (; s < NSAMP; s += gridDim.x) {
    WRITE_TILE(p);
    __syncthreads();
    int ns = s + gridDim.x;
    if (ns < NSAMP) LOAD_TILE(ns * SSTRIDE);

    f32x4 acc[4];
#pragma unroll
    for (int rf = 0; rf < 4; ++rf) acc[rf] = (f32x4)(0.f);
    COMPUTE_TILE(p);

#pragma unroll
    for (int rf = 0; rf < 4; ++rf)
#pragma unroll
      for (int j = 0; j < 4; ++j) {
        float y = acc[rf][j];
        s1a += y;
        s2a += y * y;
      }
    p ^= 1;
  }

  {
    float s1 = s1a, s2 = s2a;
    s1 += __shfl_xor(s1, 16); s2 += __shfl_xor(s2, 16);
    s1 += __shfl_xor(s1, 32); s2 += __shfl_xor(s2, 32);
    if (lane < 16) {
      atomicAdd(&colsum[w * 16 + lane], s1);
      atomicAdd(&colsumsq[w * 16 + lane], s2);
    }
  }
}

// PASS 1: zhat = y*a1 + b1f; msg = sigmoid(gate)*softplus(conv) via
// cross-lane pair (shfl_xor 8); in-register segmented scatter (lm<8 lanes);
// node ids read from double-buffered LDS
__global__ __launch_bounds__(768, 6) void k_gmsg2(
    const unsigned short* __restrict__ nb, const unsigned short* __restrict__ eb,
    const unsigned short* __restrict__ Wt, const int* __restrict__ perm,
    const int* __restrict__ i1s, const int* __restrict__ i2s,
    const float* __restrict__ a1, const float* __restrict__ b1f,
    float* __restrict__ sums) {
  __shared__ unsigned short As[2][64 * 256];  // 64 KB
  __shared__ int nidl[2][64];                 // 512 B
  GEMM_PROLOGUE();
  const float c0 = a1[w * 16 + lm];
  const float c1 = b1f[w * 16 + lm];
  const int mcol = w * 8 + (lm & 7);  // orig gate/msg column

  int tile = blockIdx.x;
  int p = 0;
  if (tile < NTILES) LOAD_TILE(tile);
  for (; tile < NTILES; tile += gridDim.x) {
    const int e0 = tile * 64;
    WRITE_TILE(p);
    if (tid < 64) nidl[p][tid] = i1s[e0 + tid];
    __syncthreads();
    int nt = tile + gridDim.x;
    if (nt < NTILES) LOAD_TILE(nt);

    f32x4 acc[4];
#pragma unroll
    for (int rf = 0; rf < 4; ++rf) acc[rf] = (f32x4)(0.f);
    COMPUTE_TILE(p);

    float run = 0.f;
    int curn = nidl[p][hi * 16];
#pragma unroll
    for (int rf = 0; rf < 4; ++rf)
#pragma unroll
      for (int j = 0; j < 4; ++j) {
        int k = rf * 4 + j;
        float z = acc[rf][j] * c0 + c1;
        float v = (lm < 8) ? sigmoidf_(z) : softplusf_(z);
        float pp = __shfl_xor(v, 8);
        run += v * pp;
        int nxt = (k < 15) ? nidl[p][hi * 16 + k + 1] : -1;
        if (nxt != curn) {
          if (lm < 8) atomicAdd(&sums[(size_t)curn * NF + mcol], run);
          run = 0.f;
          curn = nxt;
        }
      }
    p ^= 1;
  }
}

// ---------------- BN affine computation ----------------
// stats from the 200k-edge subsample (unbiased estimators of batch stats)
__global__ void k_bn1(const float* __restrict__ colsum, const float* __restrict__ colsumsq,
                      const float* __restrict__ gamma1, const float* __restrict__ beta1,
                      float* __restrict__ a1, float* __restrict__ b1f) {
  int c = threadIdx.x;  // 192, our col space
  int o = col_perm12(c);
  const float inv_n = 1.f / (float)(NSAMP * 64);
  float my = colsum[c] * inv_n;
  float v = colsumsq[c] * inv_n - my * my;
  float a = gamma1[o] * rsqrtf(v + BN_EPS);
  a1[c] = a;
  b1f[c] = beta1[o] - my * a;  // bias cancels against batch mean
}

__global__ void k_nodestats(const float* __restrict__ sums, const int* __restrict__ icounts,
                            float* __restrict__ colsum2, float* __restrict__ colsumsq2) {
  __shared__ float sh[2][2][96];
  int t = threadIdx.x;  // 192
  int c = t % 96, sub = t / 96;
  float s1 = 0.f, s2 = 0.f;
  int n0 = blockIdx.x * 256;
  for (int r = sub; r < 256; r += 2) {
    int n = n0 + r;
    if (n < N_NODES) {
      float v = sums[(size_t)n * NF + c] / fmaxf((float)icounts[n], 1.f);
      s1 += v; s2 += v * v;
    }
  }
  sh[0][sub][c] = s1; sh[1][sub][c] = s2;
  __syncthreads();
  if (sub == 0) {
    atomicAdd(&colsum2[c], s1 + sh[0][1][c]);
    atomicAdd(&colsumsq2[c], s2 + sh[1][1][c]);
  }
}

__global__ void k_bn2(const float* __restrict__ colsum2, const float* __restrict__ colsumsq2,
                      const float* __restrict__ gamma2, const float* __restrict__ beta2,
                      float* __restrict__ a2, float* __restrict__ b2f) {
  int c = threadIdx.x;
  if (c < 96) {
    float m = colsum2[c] * (1.f / N_NODES);
    float v = colsumsq2[c] * (1.f / N_NODES) - m * m;
    float a = gamma2[c] * rsqrtf(v + BN_EPS);
    a2[c] = a;
    b2f[c] = beta2[c] - m * a;
  }
}

__global__ void k_final(const float* __restrict__ node, const float* __restrict__ sums,
                        const int* __restrict__ icounts, const float* __restrict__ a2,
                        const float* __restrict__ b2f, float* __restrict__ out) {
  int stride = gridDim.x * blockDim.x;
  for (int i = blockIdx.x * blockDim.x + threadIdx.x; i < N_NODES * NF / 4; i += stride) {
    int n = i / 24, c4 = (i % 24) * 4;
    float inv = 1.f / fmaxf((float)icounts[n], 1.f);
    float4 s = reinterpret_cast<const float4*>(sums)[i];
    float4 nf = reinterpret_cast<const float4*>(node)[i];
    float4 o;
    o.x = softplusf_(nf.x + s.x * inv * a2[c4 + 0] + b2f[c4 + 0]);
    o.y = softplusf_(nf.y + s.y * inv * a2[c4 + 1] + b2f[c4 + 1]);
    o.z = softplusf_(nf.z + s.z * inv * a2[c4 + 2] + b2f[c4 + 2]);
    o.w = softplusf_(nf.w + s.w * inv * a2[c4 + 3] + b2f[c4 + 3]);
    reinterpret_cast<float4*>(out)[i] = o;
  }
}

extern "C" void kernel_launch(void* const* d_in, const int* in_sizes, int n_in,
                              void* d_out, int out_size, void* d_ws, size_t ws_size,
                              hipStream_t stream) {
  const float* node = (const float*)d_in[0];
  const float* edge = (const float*)d_in[1];
  const float* W = (const float*)d_in[2];
  const float* gamma1 = (const float*)d_in[4];
  const float* beta1 = (const float*)d_in[5];
  const float* gamma2 = (const float*)d_in[6];
  const float* beta2 = (const float*)d_in[7];
  const int* idx1 = (const int*)d_in[8];
  const int* idx2 = (const int*)d_in[9];
  float* out = (float*)d_out;

  char* ws = (char*)d_ws;
  unsigned short* nb = (unsigned short*)(ws);               //   9,600,000
  unsigned short* eb = (unsigned short*)(ws + 9600000);     // 102,400,000 (orig order)
  unsigned short* Wt = (unsigned short*)(ws + 112000000);   //      98,304
  float* sums = (float*)(ws + 112098304);                   //  19,200,000
  float* stats = (float*)(ws + 131298304);                  //       8,192
  int* icounts = (int*)(ws + 131306496);                    //     200,000
  int* perm = (int*)(ws + 131506496);                       //   3,200,000
  int* i1s = (int*)(ws + 134706496);                        //   3,200,000
  int* i2s = (int*)(ws + 137906496);                        //   3,200,000
  // total 141,106,496 bytes

  // overlay at head of sums (used only before k_gmsg2, re-zeroed after)
  int* offsets = (int*)(ws + 112098304);        // 50000 ints
  int* cursor = offsets + 50048;                // 50000 ints

  float* colsum1 = stats;          // 192
  float* colsumsq1 = stats + 192;  // 192
  float* colsum2 = stats + 384;    // 96
  float* colsumsq2 = stats + 480;  // 96
  float* a1 = stats + 576;         // 192
  float* b1f = stats + 768;        // 192
  float* a2 = stats + 960;         // 96
  float* b2f = stats + 1056;       // 96
  int* bsum = (int*)(ws + 131303424);  // 128 ints
  int* boff = (int*)(ws + 131303936);  // 128 ints

  // zero sums (incl. offsets/cursor overlay) + stats + icounts
  (void)hipMemsetAsync(ws + 112098304, 0, 19200000 + 8192 + 200000, stream);

  k_cvt<<<2048, 256, 0, stream>>>(node, nb, N_NODES * NF / 4);
  k_cvt<<<2048, 256, 0, stream>>>(edge, eb, N_EDGES * FE / 4);
  k_cvt_w<<<DOUT * DIN / 256, 256, 0, stream>>>(W, Wt);
  k_hist<<<1024, 256, 0, stream>>>(idx1, icounts);
  k_scanA<<<SCAN_NB, SCAN_B, 0, stream>>>(icounts, offsets, bsum);
  k_scanB<<<1, 128, 0, stream>>>(bsum, boff);
  k_scanC<<<SCAN_NB, SCAN_B, 0, stream>>>(offsets, boff);
  k_perm<<<1024, 256, 0, stream>>>(idx1, idx2, offsets, cursor, perm, i1s, i2s);

  k_gstats<<<512, 768, 0, stream>>>(nb, eb, Wt, perm, i1s, i2s, colsum1, colsumsq1);
  k_bn1<<<1, 192, 0, stream>>>(colsum1, colsumsq1, gamma1, beta1, a1, b1f);

  // re-zero the overlay region before atomic accumulation into sums
  (void)hipMemsetAsync(ws + 112098304, 0, 524288, stream);

  k_gmsg2<<<512, 768, 0, stream>>>(nb, eb, Wt, perm, i1s, i2s, a1, b1f, sums);

  k_nodestats<<<(N_NODES + 255) / 256, 192, 0, stream>>>(sums, icounts, colsum2, colsumsq2);
  k_bn2<<<1, 128, 0, stream>>>(colsum2, colsumsq2, gamma2, beta2, a2, b2f);
  k_final<<<2048, 256, 0, stream>>>(node, sums, icounts, a2, b2f, out);
}

// Round 18
// 546.591 us; speedup vs baseline: 1.7598x; 1.1799x over previous
//
#include <hip/hip_runtime.h>
#include <stddef.h>
#include <stdint.h>

#define N_NODES 50000
#define N_EDGES 800000
#define NF 96
#define FE 64
#define DIN 256
#define DOUT 192
#define BN_EPS 1e-5f
#define NTILES (N_EDGES / 64)
#define SSTRIDE 4                  // stats subsample: every 4th tile
#define NSAMP (NTILES / SSTRIDE)   // 3125 tiles = 200000 edges

typedef float f32x4 __attribute__((ext_vector_type(4)));
typedef short bf16x8 __attribute__((ext_vector_type(8)));

__device__ __forceinline__ unsigned short f2bf(float f) {
  unsigned int u = __float_as_uint(f);
  return (unsigned short)((u + 0x7fffu + ((u >> 16) & 1u)) >> 16);
}
__device__ __forceinline__ float sigmoidf_(float x) {
  return 1.f / (1.f + __expf(-x));
}
__device__ __forceinline__ float softplusf_(float x) {
  float t = exp2f(-fabsf(x) * 1.44269504f);
  return fmaxf(x, 0.f) + 0.69314718f * log2f(1.f + t);
}
__device__ __forceinline__ void gload_lds16(const void* g, void* l) {
  __builtin_amdgcn_global_load_lds(
      (const __attribute__((address_space(1))) void*)g,
      (__attribute__((address_space(3))) void*)l, 16, 0, 0);
}

// row permutation: A-row r holds sorted-edge e0 + rperm_(r); swaps rf<->hi so a
// thread's 16 C-fragment values are 16 CONSECUTIVE sorted edges.
__device__ __forceinline__ int rperm_(int r) {
  return ((r >> 2) & 3) * 16 + (r >> 4) * 4 + (r & 3);
}

// 12-wave col mapping: our col c' = w*16 + l (w in [0,12), l in [0,16)).
// l<8 -> gate col w*8+l ; l>=8 -> conv col 96 + w*8 + (l-8).
// => lane lm and lane lm+8 of wave w hold a gate/conv PAIR (shfl_xor(8)).
__device__ __forceinline__ int col_perm12(int c) {
  int w = c >> 4, l = c & 15;
  return (l < 8) ? (w * 8 + l) : (96 + w * 8 + l - 8);
}

// ---------------- conversion / sort kernels ----------------
__global__ void k_cvt(const float* __restrict__ in, unsigned short* __restrict__ out, int n4) {
  int stride = gridDim.x * blockDim.x;
  for (int i = blockIdx.x * blockDim.x + threadIdx.x; i < n4; i += stride) {
    float4 v = reinterpret_cast<const float4*>(in)[i];
    ushort4 o;
    o.x = f2bf(v.x); o.y = f2bf(v.y); o.z = f2bf(v.z); o.w = f2bf(v.w);
    reinterpret_cast<ushort4*>(out)[i] = o;
  }
}

__global__ void k_cvt_w(const float* __restrict__ W, unsigned short* __restrict__ Wt) {
  int i = blockIdx.x * blockDim.x + threadIdx.x;
  if (i < DOUT * DIN) {
    int c = i / DIN, k = i % DIN;
    Wt[i] = f2bf(W[k * DOUT + col_perm12(c)]);
  }
}

__global__ void k_hist(const int* __restrict__ idx1, int* __restrict__ icounts) {
  int stride = gridDim.x * blockDim.x;
  for (int e = blockIdx.x * blockDim.x + threadIdx.x; e < N_EDGES; e += stride)
    atomicAdd(&icounts[idx1[e]], 1);
}

// ---- 3-phase multi-block exclusive scan of icounts[50000] -> offsets ----
#define SCAN_B 512
#define SCAN_NB 98
__global__ void k_scanA(const int* __restrict__ ic, int* __restrict__ off,
                        int* __restrict__ bsum) {
  __shared__ int tmp[SCAN_B];
  int tid = threadIdx.x, i = blockIdx.x * SCAN_B + tid;
  int v = (i < N_NODES) ? ic[i] : 0;
  tmp[tid] = v;
  __syncthreads();
  for (int o = 1; o < SCAN_B; o <<= 1) {
    int t = (tid >= o) ? tmp[tid - o] : 0;
    __syncthreads();
    tmp[tid] += t;
    __syncthreads();
  }
  if (i < N_NODES) off[i] = tmp[tid] - v;
  if (tid == SCAN_B - 1) bsum[blockIdx.x] = tmp[tid];
}
__global__ void k_scanB(const int* __restrict__ bsum, int* __restrict__ boff) {
  __shared__ int tmp[128];
  int tid = threadIdx.x;
  int v = (tid < SCAN_NB) ? bsum[tid] : 0;
  tmp[tid] = v;
  __syncthreads();
  for (int o = 1; o < 128; o <<= 1) {
    int t = (tid >= o) ? tmp[tid - o] : 0;
    __syncthreads();
    tmp[tid] += t;
    __syncthreads();
  }
  if (tid < SCAN_NB) boff[tid] = tmp[tid] - v;
}
__global__ void k_scanC(int* __restrict__ off, const int* __restrict__ boff) {
  int i = blockIdx.x * SCAN_B + threadIdx.x;
  if (i < N_NODES) off[i] += boff[blockIdx.x];
}

// scatter edge ids into sorted-by-idx1 order; also pre-gather idx2
__global__ void k_perm(const int* __restrict__ idx1, const int* __restrict__ idx2,
                       const int* __restrict__ offsets, int* __restrict__ cursor,
                       int* __restrict__ perm, int* __restrict__ i1s,
                       int* __restrict__ i2s) {
  int stride = gridDim.x * blockDim.x;
  for (int e = blockIdx.x * blockDim.x + threadIdx.x; e < N_EDGES; e += stride) {
    int n = idx1[e];
    int p = offsets[n] + atomicAdd(&cursor[n], 1);
    perm[p] = e;
    i1s[p] = n;
    i2s[p] = idx2[e];
  }
}

// ---------------- shared GEMM machinery (12 waves x 16 cols) ----------------
// 768 threads; 64 rows/tile; A double-buffered 2x32KB; ONE barrier/tile.
// Prefetch of tile t+1 is issued via global_load_lds into buffer p^1 BEFORE
// COMPUTE(p); the compiler's vmcnt(0) drain at __syncthreads() completes it.
// Zero staging VGPRs (R15-R17 spilled on reg-staged prefetch). B fragment
// re-read from L2 per K-step through an asm-opaqued pointer (8 VGPR live).
// LDS layout: row r linear; slot cs holds global chunk cs^(r&7) (source-side
// swizzle; read with same XOR).

#define GEMM_PROLOGUE()                                                        \
  const int tid = threadIdx.x;                                                 \
  const int lane = tid & 63;                                                   \
  const int w = tid >> 6;                                                      \
  const int lm = lane & 15;                                                    \
  const int hi = lane >> 4;                                                    \
  const size_t wfoff = (size_t)(w * 16 + lm) * DIN + hi * 8;

// wave w stages rows {2w,2w+1} (k=0), {2w+24,2w+25} (k=1), {2w+48,2w+49}
// (k=2, waves 0-7 only). Wave-uniform LDS base; lane fills +lane*16 bytes.
#define STAGE_TILE(T, P)                                                       \
  {                                                                            \
    const int e0_ = (T) * 64;                                                  \
    _Pragma("unroll") for (int k = 0; k < 3; ++k) {                            \
      if (k < 2 || w < 8) {                                                    \
        int rbase = 2 * w + 24 * k;                                            \
        int r = rbase + (lane >> 5);                                           \
        int g = (lane & 31) ^ (r & 7);                                         \
        int es = e0_ + rperm_(r);                                              \
        int i1 = i1s[es];                                                      \
        int i2 = i2s[es];                                                      \
        int ep = perm[es];                                                     \
        const unsigned short* s0 = nb + (size_t)i1 * NF + g * 8;               \
        const unsigned short* s1 = nb + (size_t)i2 * NF + (g - 12) * 8;        \
        const unsigned short* s2 = eb + (size_t)ep * FE + (g - 24) * 8;        \
        const unsigned short* src = g < 12 ? s0 : (g < 24 ? s1 : s2);          \
        gload_lds16(src, &As[P][rbase * 256]);                                 \
      }                                                                        \
    }                                                                          \
  }

// per-K-step B reload through opaque pointer; rows processed in PAIRS
#define COMPUTE_TILE(P)                                                        \
  {                                                                            \
    uintptr_t wp_ = (uintptr_t)Wt;                                             \
    _Pragma("unroll") for (int ks = 0; ks < 8; ++ks) {                         \
      asm volatile("" : "+s"(wp_));                                            \
      const unsigned short* Wo = (const unsigned short*)wp_;                   \
      bf16x8 bfr = *reinterpret_cast<const bf16x8*>(Wo + wfoff + ks * 32);     \
      int slot = (ks * 4 + hi) ^ (lm & 7);                                     \
      {                                                                        \
        bf16x8 a0 = *reinterpret_cast<const bf16x8*>(                          \
            &As[P][(0 * 16 + lm) * 256 + slot * 8]);                           \
        bf16x8 a1 = *reinterpret_cast<const bf16x8*>(                          \
            &As[P][(1 * 16 + lm) * 256 + slot * 8]);                           \
        acc[0] = __builtin_amdgcn_mfma_f32_16x16x32_bf16(a0, bfr, acc[0], 0, 0, 0); \
        acc[1] = __builtin_amdgcn_mfma_f32_16x16x32_bf16(a1, bfr, acc[1], 0, 0, 0); \
      }                                                                        \
      {                                                                        \
        bf16x8 a0 = *reinterpret_cast<const bf16x8*>(                          \
            &As[P][(2 * 16 + lm) * 256 + slot * 8]);                           \
        bf16x8 a1 = *reinterpret_cast<const bf16x8*>(                          \
            &As[P][(3 * 16 + lm) * 256 + slot * 8]);                           \
        acc[2] = __builtin_amdgcn_mfma_f32_16x16x32_bf16(a0, bfr, acc[2], 0, 0, 0); \
        acc[3] = __builtin_amdgcn_mfma_f32_16x16x32_bf16(a1, bfr, acc[3], 0, 0, 0); \
      }                                                                        \
    }                                                                          \
  }

// PASS 0: column stats of y = XW over stride-4 tile subsample (200k edges)
__global__ __launch_bounds__(768, 6) void k_gstats(
    const unsigned short* __restrict__ nb, const unsigned short* __restrict__ eb,
    const unsigned short* __restrict__ Wt, const int* __restrict__ perm,
    const int* __restrict__ i1s, const int* __restrict__ i2s,
    float* __restrict__ colsum, float* __restrict__ colsumsq) {
  __shared__ unsigned short As[2][64 * 256];  // 64 KB
  GEMM_PROLOGUE();
  float s1a = 0.f, s2a = 0.f;

  int s = blockIdx.x;
  int p = 0;
  if (s < NSAMP) STAGE_TILE(s * SSTRIDE, 0);
  __syncthreads();
  for (; s < NSAMP; s += gridDim.x) {
    int ns = s + gridDim.x;
    if (ns < NSAMP) STAGE_TILE(ns * SSTRIDE, p ^ 1);

    f32x4 acc[4];
#pragma unroll
    for (int rf = 0; rf < 4; ++rf) acc[rf] = (f32x4)(0.f);
    COMPUTE_TILE(p);

#pragma unroll
    for (int rf = 0; rf < 4; ++rf)
#pragma unroll
      for (int j = 0; j < 4; ++j) {
        float y = acc[rf][j];
        s1a += y;
        s2a += y * y;
      }
    __syncthreads();
    p ^= 1;
  }

  {
    float s1 = s1a, s2 = s2a;
    s1 += __shfl_xor(s1, 16); s2 += __shfl_xor(s2, 16);
    s1 += __shfl_xor(s1, 32); s2 += __shfl_xor(s2, 32);
    if (lane < 16) {
      atomicAdd(&colsum[w * 16 + lane], s1);
      atomicAdd(&colsumsq[w * 16 + lane], s2);
    }
  }
}

// PASS 1: zhat = y*a1 + b1f; msg = sigmoid(gate)*softplus(conv) via
// cross-lane pair (shfl_xor 8); in-register segmented scatter (lm<8 lanes);
// node ids in double-buffered LDS, loaded during the stage phase
__global__ __launch_bounds__(768, 6) void k_gmsg2(
    const unsigned short* __restrict__ nb, const unsigned short* __restrict__ eb,
    const unsigned short* __restrict__ Wt, const int* __restrict__ perm,
    const int* __restrict__ i1s, const int* __restrict__ i2s,
    const float* __restrict__ a1, const float* __restrict__ b1f,
    float* __restrict__ sums) {
  __shared__ unsigned short As[2][64 * 256];  // 64 KB
  __shared__ int nidl[2][64];                 // 512 B
  GEMM_PROLOGUE();
  const float c0 = a1[w * 16 + lm];
  const float c1 = b1f[w * 16 + lm];
  const int mcol = w * 8 + (lm & 7);  // orig gate/msg column

  int tile = blockIdx.x;
  int p = 0;
  if (tile < NTILES) {
    STAGE_TILE(tile, 0);
    if (tid < 64) nidl[0][tid] = i1s[tile * 64 + tid];
  }
  __syncthreads();
  for (; tile < NTILES; tile += gridDim.x) {
    int nt = tile + gridDim.x;
    if (nt < NTILES) {
      STAGE_TILE(nt, p ^ 1);
      if (tid < 64) nidl[p ^ 1][tid] = i1s[nt * 64 + tid];
    }

    f32x4 acc[4];
#pragma unroll
    for (int rf = 0; rf < 4; ++rf) acc[rf] = (f32x4)(0.f);
    COMPUTE_TILE(p);

    float run = 0.f;
    int curn = nidl[p][hi * 16];
#pragma unroll
    for (int rf = 0; rf < 4; ++rf)
#pragma unroll
      for (int j = 0; j < 4; ++j) {
        int k = rf * 4 + j;
        float z = acc[rf][j] * c0 + c1;
        float v = (lm < 8) ? sigmoidf_(z) : softplusf_(z);
        float pp = __shfl_xor(v, 8);
        run += v * pp;
        int nxt = (k < 15) ? nidl[p][hi * 16 + k + 1] : -1;
        if (nxt != curn) {
          if (lm < 8) atomicAdd(&sums[(size_t)curn * NF + mcol], run);
          run = 0.f;
          curn = nxt;
        }
      }
    __syncthreads();
    p ^= 1;
  }
}

// ---------------- BN affine computation ----------------
// stats from the 200k-edge subsample (unbiased estimators of batch stats)
__global__ void k_bn1(const float* __restrict__ colsum, const float* __restrict__ colsumsq,
                      const float* __restrict__ gamma1, const float* __restrict__ beta1,
                      float* __restrict__ a1, float* __restrict__ b1f) {
  int c = threadIdx.x;  // 192, our col space
  int o = col_perm12(c);
  const float inv_n = 1.f / (float)(NSAMP * 64);
  float my = colsum[c] * inv_n;
  float v = colsumsq[c] * inv_n - my * my;
  float a = gamma1[o] * rsqrtf(v + BN_EPS);
  a1[c] = a;
  b1f[c] = beta1[o] - my * a;  // bias cancels against batch mean
}

__global__ void k_nodestats(const float* __restrict__ sums, const int* __restrict__ icounts,
                            float* __restrict__ colsum2, float* __restrict__ colsumsq2) {
  __shared__ float sh[2][2][96];
  int t = threadIdx.x;  // 192
  int c = t % 96, sub = t / 96;
  float s1 = 0.f, s2 = 0.f;
  int n0 = blockIdx.x * 256;
  for (int r = sub; r < 256; r += 2) {
    int n = n0 + r;
    if (n < N_NODES) {
      float v = sums[(size_t)n * NF + c] / fmaxf((float)icounts[n], 1.f);
      s1 += v; s2 += v * v;
    }
  }
  sh[0][sub][c] = s1; sh[1][sub][c] = s2;
  __syncthreads();
  if (sub == 0) {
    atomicAdd(&colsum2[c], s1 + sh[0][1][c]);
    atomicAdd(&colsumsq2[c], s2 + sh[1][1][c]);
  }
}

__global__ void k_bn2(const float* __restrict__ colsum2, const float* __restrict__ colsumsq2,
                      const float* __restrict__ gamma2, const float* __restrict__ beta2,
                      float* __restrict__ a2, float* __restrict__ b2f) {
  int c = threadIdx.x;
  if (c < 96) {
    float m = colsum2[c] * (1.f / N_NODES);
    float v = colsumsq2[c] * (1.f / N_NODES) - m * m;
    float a = gamma2[c] * rsqrtf(v + BN_EPS);
    a2[c] = a;
    b2f[c] = beta2[c] - m * a;
  }
}

__global__ void k_final(const float* __restrict__ node, const float* __restrict__ sums,
                        const int* __restrict__ icounts, const float* __restrict__ a2,
                        const float* __restrict__ b2f, float* __restrict__ out) {
  int stride = gridDim.x * blockDim.x;
  for (int i = blockIdx.x * blockDim.x + threadIdx.x; i < N_NODES * NF / 4; i += stride) {
    int n = i / 24, c4 = (i % 24) * 4;
    float inv = 1.f / fmaxf((float)icounts[n], 1.f);
    float4 s = reinterpret_cast<const float4*>(sums)[i];
    float4 nf = reinterpret_cast<const float4*>(node)[i];
    float4 o;
    o.x = softplusf_(nf.x + s.x * inv * a2[c4 + 0] + b2f[c4 + 0]);
    o.y = softplusf_(nf.y + s.y * inv * a2[c4 + 1] + b2f[c4 + 1]);
    o.z = softplusf_(nf.z + s.z * inv * a2[c4 + 2] + b2f[c4 + 2]);
    o.w = softplusf_(nf.w + s.w * inv * a2[c4 + 3] + b2f[c4 + 3]);
    reinterpret_cast<float4*>(out)[i] = o;
  }
}

extern "C" void kernel_launch(void* const* d_in, const int* in_sizes, int n_in,
                              void* d_out, int out_size, void* d_ws, size_t ws_size,
                              hipStream_t stream) {
  const float* node = (const float*)d_in[0];
  const float* edge = (const float*)d_in[1];
  const float* W = (const float*)d_in[2];
  const float* gamma1 = (const float*)d_in[4];
  const float* beta1 = (const float*)d_in[5];
  const float* gamma2 = (const float*)d_in[6];
  const float* beta2 = (const float*)d_in[7];
  const int* idx1 = (const int*)d_in[8];
  const int* idx2 = (const int*)d_in[9];
  float* out = (float*)d_out;

  char* ws = (char*)d_ws;
  unsigned short* nb = (unsigned short*)(ws);               //   9,600,000
  unsigned short* eb = (unsigned short*)(ws + 9600000);     // 102,400,000 (orig order)
  unsigned short* Wt = (unsigned short*)(ws + 112000000);   //      98,304
  float* sums = (float*)(ws + 112098304);                   //  19,200,000
  float* stats = (float*)(ws + 131298304);                  //       8,192
  int* icounts = (int*)(ws + 131306496);                    //     200,000
  int* perm = (int*)(ws + 131506496);                       //   3,200,000
  int* i1s = (int*)(ws + 134706496);                        //   3,200,000
  int* i2s = (int*)(ws + 137906496);                        //   3,200,000
  // total 141,106,496 bytes

  // overlay at head of sums (used only before k_gmsg2, re-zeroed after)
  int* offsets = (int*)(ws + 112098304);        // 50000 ints
  int* cursor = offsets + 50048;                // 50000 ints

  float* colsum1 = stats;          // 192
  float* colsumsq1 = stats + 192;  // 192
  float* colsum2 = stats + 384;    // 96
  float* colsumsq2 = stats + 480;  // 96
  float* a1 = stats + 576;         // 192
  float* b1f = stats + 768;        // 192
  float* a2 = stats + 960;         // 96
  float* b2f = stats + 1056;       // 96
  int* bsum = (int*)(ws + 131303424);  // 128 ints
  int* boff = (int*)(ws + 131303936);  // 128 ints

  // zero sums (incl. offsets/cursor overlay) + stats + icounts
  (void)hipMemsetAsync(ws + 112098304, 0, 19200000 + 8192 + 200000, stream);

  k_cvt<<<2048, 256, 0, stream>>>(node, nb, N_NODES * NF / 4);
  k_cvt<<<2048, 256, 0, stream>>>(edge, eb, N_EDGES * FE / 4);
  k_cvt_w<<<DOUT * DIN / 256, 256, 0, stream>>>(W, Wt);
  k_hist<<<1024, 256, 0, stream>>>(idx1, icounts);
  k_scanA<<<SCAN_NB, SCAN_B, 0, stream>>>(icounts, offsets, bsum);
  k_scanB<<<1, 128, 0, stream>>>(bsum, boff);
  k_scanC<<<SCAN_NB, SCAN_B, 0, stream>>>(offsets, boff);
  k_perm<<<1024, 256, 0, stream>>>(idx1, idx2, offsets, cursor, perm, i1s, i2s);

  k_gstats<<<512, 768, 0, stream>>>(nb, eb, Wt, perm, i1s, i2s, colsum1, colsumsq1);
  k_bn1<<<1, 192, 0, stream>>>(colsum1, colsumsq1, gamma1, beta1, a1, b1f);

  // re-zero the overlay region before atomic accumulation into sums
  (void)hipMemsetAsync(ws + 112098304, 0, 524288, stream);

  k_gmsg2<<<512, 768, 0, stream>>>(nb, eb, Wt, perm, i1s, i2s, a1, b1f, sums);

  k_nodestats<<<(N_NODES + 255) / 256, 192, 0, stream>>>(sums, icounts, colsum2, colsumsq2);
  k_bn2<<<1, 128, 0, stream>>>(colsum2, colsumsq2, gamma2, beta2, a2, b2f);
  k_final<<<2048, 256, 0, stream>>>(node, sums, icounts, a2, b2f, out);
}

// Round 19
// 516.481 us; speedup vs baseline: 1.8624x; 1.0583x over previous
//
#include <hip/hip_runtime.h>
#include <stddef.h>
#include <stdint.h>

#define N_NODES 50000
#define N_EDGES 800000
#define NF 96
#define FE 64
#define DIN 256
#define DOUT 192
#define BN_EPS 1e-5f
#define NTILES (N_EDGES / 64)
#define SSTRIDE 8                  // stats subsample: every 8th tile
#define NSAMP (NTILES / SSTRIDE)   // 1562 tiles = 99,968 edges

typedef float f32x4 __attribute__((ext_vector_type(4)));
typedef short bf16x8 __attribute__((ext_vector_type(8)));

__device__ __forceinline__ unsigned short f2bf(float f) {
  unsigned int u = __float_as_uint(f);
  return (unsigned short)((u + 0x7fffu + ((u >> 16) & 1u)) >> 16);
}
__device__ __forceinline__ float sigmoidf_(float x) {
  return 1.f / (1.f + __expf(-x));
}
__device__ __forceinline__ float softplusf_(float x) {
  float t = exp2f(-fabsf(x) * 1.44269504f);
  return fmaxf(x, 0.f) + 0.69314718f * log2f(1.f + t);
}
__device__ __forceinline__ void gload_lds16(const void* g, void* l) {
  __builtin_amdgcn_global_load_lds(
      (const __attribute__((address_space(1))) void*)g,
      (__attribute__((address_space(3))) void*)l, 16, 0, 0);
}

// row permutation: A-row r holds sorted-edge e0 + rperm_(r); swaps rf<->hi so a
// thread's 16 C-fragment values are 16 CONSECUTIVE sorted edges.
__device__ __forceinline__ int rperm_(int r) {
  return ((r >> 2) & 3) * 16 + (r >> 4) * 4 + (r & 3);
}

// 12-wave col mapping: our col c' = w*16 + l (w in [0,12), l in [0,16)).
// l<8 -> gate col w*8+l ; l>=8 -> conv col 96 + w*8 + (l-8).
// => lane lm and lane lm+8 of wave w hold a gate/conv PAIR (shfl_xor(8)).
__device__ __forceinline__ int col_perm12(int c) {
  int w = c >> 4, l = c & 15;
  return (l < 8) ? (w * 8 + l) : (96 + w * 8 + l - 8);
}

// ---------------- conversion / sort kernels ----------------
// node features + W in one kernel
__global__ void k_cvt_nw(const float* __restrict__ node, const float* __restrict__ W,
                         unsigned short* __restrict__ nb, unsigned short* __restrict__ Wt) {
  const int NN4 = N_NODES * NF / 4;
  int stride = gridDim.x * blockDim.x;
  for (int i = blockIdx.x * blockDim.x + threadIdx.x; i < NN4 + DOUT * DIN; i += stride) {
    if (i < NN4) {
      float4 v = reinterpret_cast<const float4*>(node)[i];
      ushort4 o;
      o.x = f2bf(v.x); o.y = f2bf(v.y); o.z = f2bf(v.z); o.w = f2bf(v.w);
      reinterpret_cast<ushort4*>(nb)[i] = o;
    } else {
      int j = i - NN4;
      int c = j / DIN, k = j % DIN;
      Wt[j] = f2bf(W[k * DOUT + col_perm12(c)]);
    }
  }
}

// edge features + idx1 histogram in one kernel
__global__ void k_cvt_e(const float* __restrict__ edge, const int* __restrict__ idx1,
                        unsigned short* __restrict__ eb, int* __restrict__ icounts) {
  const int NE4 = N_EDGES * FE / 4;
  int stride = gridDim.x * blockDim.x;
  for (int i = blockIdx.x * blockDim.x + threadIdx.x; i < NE4; i += stride) {
    float4 v = reinterpret_cast<const float4*>(edge)[i];
    ushort4 o;
    o.x = f2bf(v.x); o.y = f2bf(v.y); o.z = f2bf(v.z); o.w = f2bf(v.w);
    reinterpret_cast<ushort4*>(eb)[i] = o;
  }
  for (int e = blockIdx.x * blockDim.x + threadIdx.x; e < N_EDGES; e += stride)
    atomicAdd(&icounts[idx1[e]], 1);
}

// ---- 3-phase multi-block exclusive scan of icounts[50000] -> offsets ----
#define SCAN_B 512
#define SCAN_NB 98
__global__ void k_scanA(const int* __restrict__ ic, int* __restrict__ off,
                        int* __restrict__ bsum) {
  __shared__ int tmp[SCAN_B];
  int tid = threadIdx.x, i = blockIdx.x * SCAN_B + tid;
  int v = (i < N_NODES) ? ic[i] : 0;
  tmp[tid] = v;
  __syncthreads();
  for (int o = 1; o < SCAN_B; o <<= 1) {
    int t = (tid >= o) ? tmp[tid - o] : 0;
    __syncthreads();
    tmp[tid] += t;
    __syncthreads();
  }
  if (i < N_NODES) off[i] = tmp[tid] - v;
  if (tid == SCAN_B - 1) bsum[blockIdx.x] = tmp[tid];
}
__global__ void k_scanB(const int* __restrict__ bsum, int* __restrict__ boff) {
  __shared__ int tmp[128];
  int tid = threadIdx.x;
  int v = (tid < SCAN_NB) ? bsum[tid] : 0;
  tmp[tid] = v;
  __syncthreads();
  for (int o = 1; o < 128; o <<= 1) {
    int t = (tid >= o) ? tmp[tid - o] : 0;
    __syncthreads();
    tmp[tid] += t;
    __syncthreads();
  }
  if (tid < SCAN_NB) boff[tid] = tmp[tid] - v;
}
__global__ void k_scanC(int* __restrict__ off, const int* __restrict__ boff) {
  int i = blockIdx.x * SCAN_B + threadIdx.x;
  if (i < N_NODES) off[i] += boff[blockIdx.x];
}

// scatter edge ids into sorted-by-idx1 order; also pre-gather idx2
__global__ void k_perm(const int* __restrict__ idx1, const int* __restrict__ idx2,
                       const int* __restrict__ offsets, int* __restrict__ cursor,
                       int* __restrict__ perm, int* __restrict__ i1s,
                       int* __restrict__ i2s) {
  int stride = gridDim.x * blockDim.x;
  for (int e = blockIdx.x * blockDim.x + threadIdx.x; e < N_EDGES; e += stride) {
    int n = idx1[e];
    int p = offsets[n] + atomicAdd(&cursor[n], 1);
    perm[p] = e;
    i1s[p] = n;
    i2s[p] = idx2[e];
  }
}

// ---------------- shared GEMM machinery (12 waves x 16 cols) ----------------
// 768 threads; 64 rows/tile; A double-buffered 2x32KB; ONE barrier/tile.
// Prefetch of tile t+1 via global_load_lds into buffer p^1 BEFORE COMPUTE(p);
// the vmcnt(0) drain at __syncthreads() completes it. Zero staging VGPRs.
// B fragment re-read from L2 per K-step via asm-opaqued pointer (8 VGPR live).
// LDS: row r linear; slot cs holds global chunk cs^(r&7) (src-side swizzle).

#define GEMM_PROLOGUE()                                                        \
  const int tid = threadIdx.x;                                                 \
  const int lane = tid & 63;                                                   \
  const int w = tid >> 6;                                                      \
  const int lm = lane & 15;                                                    \
  const int hi = lane >> 4;                                                    \
  const size_t wfoff = (size_t)(w * 16 + lm) * DIN + hi * 8;

#define STAGE_TILE(T, P)                                                       \
  {                                                                            \
    const int e0_ = (T) * 64;                                                  \
    _Pragma("unroll") for (int k = 0; k < 3; ++k) {                            \
      if (k < 2 || w < 8) {                                                    \
        int rbase = 2 * w + 24 * k;                                            \
        int r = rbase + (lane >> 5);                                           \
        int g = (lane & 31) ^ (r & 7);                                         \
        int es = e0_ + rperm_(r);                                              \
        int i1 = i1s[es];                                                      \
        int i2 = i2s[es];                                                      \
        int ep = perm[es];                                                     \
        const unsigned short* s0 = nb + (size_t)i1 * NF + g * 8;               \
        const unsigned short* s1 = nb + (size_t)i2 * NF + (g - 12) * 8;        \
        const unsigned short* s2 = eb + (size_t)ep * FE + (g - 24) * 8;        \
        const unsigned short* src = g < 12 ? s0 : (g < 24 ? s1 : s2);          \
        gload_lds16(src, &As[P][rbase * 256]);                                 \
      }                                                                        \
    }                                                                          \
  }

#define COMPUTE_TILE(P)                                                        \
  {                                                                            \
    uintptr_t wp_ = (uintptr_t)Wt;                                             \
    _Pragma("unroll") for (int ks = 0; ks < 8; ++ks) {                         \
      asm volatile("" : "+s"(wp_));                                            \
      const unsigned short* Wo = (const unsigned short*)wp_;                   \
      bf16x8 bfr = *reinterpret_cast<const bf16x8*>(Wo + wfoff + ks * 32);     \
      int slot = (ks * 4 + hi) ^ (lm & 7);                                     \
      {                                                                        \
        bf16x8 a0 = *reinterpret_cast<const bf16x8*>(                          \
            &As[P][(0 * 16 + lm) * 256 + slot * 8]);                           \
        bf16x8 a1 = *reinterpret_cast<const bf16x8*>(                          \
            &As[P][(1 * 16 + lm) * 256 + slot * 8]);                           \
        acc[0] = __builtin_amdgcn_mfma_f32_16x16x32_bf16(a0, bfr, acc[0], 0, 0, 0); \
        acc[1] = __builtin_amdgcn_mfma_f32_16x16x32_bf16(a1, bfr, acc[1], 0, 0, 0); \
      }                                                                        \
      {                                                                        \
        bf16x8 a0 = *reinterpret_cast<const bf16x8*>(                          \
            &As[P][(2 * 16 + lm) * 256 + slot * 8]);                           \
        bf16x8 a1 = *reinterpret_cast<const bf16x8*>(                          \
            &As[P][(3 * 16 + lm) * 256 + slot * 8]);                           \
        acc[2] = __builtin_amdgcn_mfma_f32_16x16x32_bf16(a0, bfr, acc[2], 0, 0, 0); \
        acc[3] = __builtin_amdgcn_mfma_f32_16x16x32_bf16(a1, bfr, acc[3], 0, 0, 0); \
      }                                                                        \
    }                                                                          \
  }

// PASS 0: column stats of y = XW over stride-8 tile subsample (100k edges)
__global__ __launch_bounds__(768, 6) void k_gstats(
    const unsigned short* __restrict__ nb, const unsigned short* __restrict__ eb,
    const unsigned short* __restrict__ Wt, const int* __restrict__ perm,
    const int* __restrict__ i1s, const int* __restrict__ i2s,
    float* __restrict__ colsum, float* __restrict__ colsumsq) {
  __shared__ unsigned short As[2][64 * 256];  // 64 KB
  GEMM_PROLOGUE();
  float s1a = 0.f, s2a = 0.f;

  int s = blockIdx.x;
  int p = 0;
  if (s < NSAMP) STAGE_TILE(s * SSTRIDE, 0);
  __syncthreads();
  for (; s < NSAMP; s += gridDim.x) {
    int ns = s + gridDim.x;
    if (ns < NSAMP) STAGE_TILE(ns * SSTRIDE, p ^ 1);

    f32x4 acc[4];
#pragma unroll
    for (int rf = 0; rf < 4; ++rf) acc[rf] = (f32x4)(0.f);
    COMPUTE_TILE(p);

#pragma unroll
    for (int rf = 0; rf < 4; ++rf)
#pragma unroll
      for (int j = 0; j < 4; ++j) {
        float y = acc[rf][j];
        s1a += y;
        s2a += y * y;
      }
    __syncthreads();
    p ^= 1;
  }

  {
    float s1 = s1a, s2 = s2a;
    s1 += __shfl_xor(s1, 16); s2 += __shfl_xor(s2, 16);
    s1 += __shfl_xor(s1, 32); s2 += __shfl_xor(s2, 32);
    if (lane < 16) {
      atomicAdd(&colsum[w * 16 + lane], s1);
      atomicAdd(&colsumsq[w * 16 + lane], s2);
    }
  }
}

// PASS 1: zhat = y*a1 + b1f; msg = sigmoid(gate)*softplus(conv) via
// cross-lane pair (shfl_xor 8); in-register segmented scatter (lm<8 lanes);
// node ids in double-buffered LDS, loaded during the stage phase
__global__ __launch_bounds__(768, 6) void k_gmsg2(
    const unsigned short* __restrict__ nb, const unsigned short* __restrict__ eb,
    const unsigned short* __restrict__ Wt, const int* __restrict__ perm,
    const int* __restrict__ i1s, const int* __restrict__ i2s,
    const float* __restrict__ a1, const float* __restrict__ b1f,
    float* __restrict__ sums) {
  __shared__ unsigned short As[2][64 * 256];  // 64 KB
  __shared__ int nidl[2][64];                 // 512 B
  GEMM_PROLOGUE();
  const float c0 = a1[w * 16 + lm];
  const float c1 = b1f[w * 16 + lm];
  const int mcol = w * 8 + (lm & 7);  // orig gate/msg column

  int tile = blockIdx.x;
  int p = 0;
  if (tile < NTILES) {
    STAGE_TILE(tile, 0);
    if (tid < 64) nidl[0][tid] = i1s[tile * 64 + tid];
  }
  __syncthreads();
  for (; tile < NTILES; tile += gridDim.x) {
    int nt = tile + gridDim.x;
    if (nt < NTILES) {
      STAGE_TILE(nt, p ^ 1);
      if (tid < 64) nidl[p ^ 1][tid] = i1s[nt * 64 + tid];
    }

    f32x4 acc[4];
#pragma unroll
    for (int rf = 0; rf < 4; ++rf) acc[rf] = (f32x4)(0.f);
    COMPUTE_TILE(p);

    float run = 0.f;
    int curn = nidl[p][hi * 16];
#pragma unroll
    for (int rf = 0; rf < 4; ++rf)
#pragma unroll
      for (int j = 0; j < 4; ++j) {
        int k = rf * 4 + j;
        float z = acc[rf][j] * c0 + c1;
        float v = (lm < 8) ? sigmoidf_(z) : softplusf_(z);
        float pp = __shfl_xor(v, 8);
        run += v * pp;
        int nxt = (k < 15) ? nidl[p][hi * 16 + k + 1] : -1;
        if (nxt != curn) {
          if (lm < 8) atomicAdd(&sums[(size_t)curn * NF + mcol], run);
          run = 0.f;
          curn = nxt;
        }
      }
    __syncthreads();
    p ^= 1;
  }
}

// ---------------- BN affine computation ----------------
// stats from the ~100k-edge subsample (unbiased estimators of batch stats)
__global__ void k_bn1(const float* __restrict__ colsum, const float* __restrict__ colsumsq,
                      const float* __restrict__ gamma1, const float* __restrict__ beta1,
                      float* __restrict__ a1, float* __restrict__ b1f) {
  int c = threadIdx.x;  // 192, our col space
  int o = col_perm12(c);
  const float inv_n = 1.f / (float)(NSAMP * 64);
  float my = colsum[c] * inv_n;
  float v = colsumsq[c] * inv_n - my * my;
  float a = gamma1[o] * rsqrtf(v + BN_EPS);
  a1[c] = a;
  b1f[c] = beta1[o] - my * a;  // bias cancels against batch mean
}

__global__ void k_nodestats(const float* __restrict__ sums, const int* __restrict__ icounts,
                            float* __restrict__ colsum2, float* __restrict__ colsumsq2) {
  __shared__ float sh[2][2][96];
  int t = threadIdx.x;  // 192
  int c = t % 96, sub = t / 96;
  float s1 = 0.f, s2 = 0.f;
  int n0 = blockIdx.x * 256;
  for (int r = sub; r < 256; r += 2) {
    int n = n0 + r;
    if (n < N_NODES) {
      float v = sums[(size_t)n * NF + c] / fmaxf((float)icounts[n], 1.f);
      s1 += v; s2 += v * v;
    }
  }
  sh[0][sub][c] = s1; sh[1][sub][c] = s2;
  __syncthreads();
  if (sub == 0) {
    atomicAdd(&colsum2[c], s1 + sh[0][1][c]);
    atomicAdd(&colsumsq2[c], s2 + sh[1][1][c]);
  }
}

__global__ void k_bn2(const float* __restrict__ colsum2, const float* __restrict__ colsumsq2,
                      const float* __restrict__ gamma2, const float* __restrict__ beta2,
                      float* __restrict__ a2, float* __restrict__ b2f) {
  int c = threadIdx.x;
  if (c < 96) {
    float m = colsum2[c] * (1.f / N_NODES);
    float v = colsumsq2[c] * (1.f / N_NODES) - m * m;
    float a = gamma2[c] * rsqrtf(v + BN_EPS);
    a2[c] = a;
    b2f[c] = beta2[c] - m * a;
  }
}

__global__ void k_final(const float* __restrict__ node, const float* __restrict__ sums,
                        const int* __restrict__ icounts, const float* __restrict__ a2,
                        const float* __restrict__ b2f, float* __restrict__ out) {
  int stride = gridDim.x * blockDim.x;
  for (int i = blockIdx.x * blockDim.x + threadIdx.x; i < N_NODES * NF / 4; i += stride) {
    int n = i / 24, c4 = (i % 24) * 4;
    float inv = 1.f / fmaxf((float)icounts[n], 1.f);
    float4 s = reinterpret_cast<const float4*>(sums)[i];
    float4 nf = reinterpret_cast<const float4*>(node)[i];
    float4 o;
    o.x = softplusf_(nf.x + s.x * inv * a2[c4 + 0] + b2f[c4 + 0]);
    o.y = softplusf_(nf.y + s.y * inv * a2[c4 + 1] + b2f[c4 + 1]);
    o.z = softplusf_(nf.z + s.z * inv * a2[c4 + 2] + b2f[c4 + 2]);
    o.w = softplusf_(nf.w + s.w * inv * a2[c4 + 3] + b2f[c4 + 3]);
    reinterpret_cast<float4*>(out)[i] = o;
  }
}

extern "C" void kernel_launch(void* const* d_in, const int* in_sizes, int n_in,
                              void* d_out, int out_size, void* d_ws, size_t ws_size,
                              hipStream_t stream) {
  const float* node = (const float*)d_in[0];
  const float* edge = (const float*)d_in[1];
  const float* W = (const float*)d_in[2];
  const float* gamma1 = (const float*)d_in[4];
  const float* beta1 = (const float*)d_in[5];
  const float* gamma2 = (const float*)d_in[6];
  const float* beta2 = (const float*)d_in[7];
  const int* idx1 = (const int*)d_in[8];
  const int* idx2 = (const int*)d_in[9];
  float* out = (float*)d_out;

  char* ws = (char*)d_ws;
  unsigned short* nb = (unsigned short*)(ws);               //   9,600,000
  unsigned short* eb = (unsigned short*)(ws + 9600000);     // 102,400,000 (orig order)
  unsigned short* Wt = (unsigned short*)(ws + 112000000);   //      98,304
  float* sums = (float*)(ws + 112098304);                   //  19,200,000
  float* stats = (float*)(ws + 131298304);                  //       8,192
  int* icounts = (int*)(ws + 131306496);                    //     200,000
  int* perm = (int*)(ws + 131506496);                       //   3,200,000
  int* i1s = (int*)(ws + 134706496);                        //   3,200,000
  int* i2s = (int*)(ws + 137906496);                        //   3,200,000
  // total 141,106,496 bytes

  // overlay at head of sums (used only before k_gmsg2, re-zeroed after)
  int* offsets = (int*)(ws + 112098304);        // 50000 ints
  int* cursor = offsets + 50048;                // 50000 ints

  float* colsum1 = stats;          // 192
  float* colsumsq1 = stats + 192;  // 192
  float* colsum2 = stats + 384;    // 96
  float* colsumsq2 = stats + 480;  // 96
  float* a1 = stats + 576;         // 192
  float* b1f = stats + 768;        // 192
  float* a2 = stats + 960;         // 96
  float* b2f = stats + 1056;       // 96
  int* bsum = (int*)(ws + 131303424);  // 128 ints
  int* boff = (int*)(ws + 131303936);  // 128 ints

  // zero sums (incl. offsets/cursor overlay) + stats + icounts
  (void)hipMemsetAsync(ws + 112098304, 0, 19200000 + 8192 + 200000, stream);

  k_cvt_nw<<<2048, 256, 0, stream>>>(node, W, nb, Wt);
  k_cvt_e<<<2048, 256, 0, stream>>>(edge, idx1, eb, icounts);
  k_scanA<<<SCAN_NB, SCAN_B, 0, stream>>>(icounts, offsets, bsum);
  k_scanB<<<1, 128, 0, stream>>>(bsum, boff);
  k_scanC<<<SCAN_NB, SCAN_B, 0, stream>>>(offsets, boff);
  k_perm<<<1024, 256, 0, stream>>>(idx1, idx2, offsets, cursor, perm, i1s, i2s);

  k_gstats<<<512, 768, 0, stream>>>(nb, eb, Wt, perm, i1s, i2s, colsum1, colsumsq1);
  k_bn1<<<1, 192, 0, stream>>>(colsum1, colsumsq1, gamma1, beta1, a1, b1f);

  // re-zero the overlay region before atomic accumulation into sums
  (void)hipMemsetAsync(ws + 112098304, 0, 524288, stream);

  k_gmsg2<<<512, 768, 0, stream>>>(nb, eb, Wt, perm, i1s, i2s, a1, b1f, sums);

  k_nodestats<<<(N_NODES + 255) / 256, 192, 0, stream>>>(sums, icounts, colsum2, colsumsq2);
  k_bn2<<<1, 128, 0, stream>>>(colsum2, colsumsq2, gamma2, beta2, a2, b2f);
  k_final<<<2048, 256, 0, stream>>>(node, sums, icounts, a2, b2f, out);
}

// Round 20
// 469.464 us; speedup vs baseline: 2.0489x; 1.1001x over previous
//
#include <hip/hip_runtime.h>
#include <stddef.h>
#include <stdint.h>

#define N_NODES 50000
#define N_EDGES 800000
#define NF 96
#define FE 64
#define DIN 256
#define DOUT 192
#define BN_EPS 1e-5f
#define NTILES (N_EDGES / 64)
#define SSTRIDE 16                 // stats subsample: every 16th tile
#define NSAMP (NTILES / SSTRIDE)   // 781 tiles = 49,984 edges

typedef float f32x4 __attribute__((ext_vector_type(4)));
typedef short bf16x8 __attribute__((ext_vector_type(8)));

__device__ __forceinline__ unsigned short f2bf(float f) {
  unsigned int u = __float_as_uint(f);
  return (unsigned short)((u + 0x7fffu + ((u >> 16) & 1u)) >> 16);
}
__device__ __forceinline__ float sigmoidf_(float x) {
  return 1.f / (1.f + __expf(-x));
}
__device__ __forceinline__ float softplusf_(float x) {
  float t = exp2f(-fabsf(x) * 1.44269504f);
  return fmaxf(x, 0.f) + 0.69314718f * log2f(1.f + t);
}
__device__ __forceinline__ void gload_lds16(const void* g, void* l) {
  __builtin_amdgcn_global_load_lds(
      (const __attribute__((address_space(1))) void*)g,
      (__attribute__((address_space(3))) void*)l, 16, 0, 0);
}

// row permutation: A-row r holds sorted-edge e0 + rperm_(r); swaps rf<->hi so a
// thread's 16 C-fragment values are 16 CONSECUTIVE sorted edges.
__device__ __forceinline__ int rperm_(int r) {
  return ((r >> 2) & 3) * 16 + (r >> 4) * 4 + (r & 3);
}

// 12-wave col mapping: our col c' = w*16 + l (w in [0,12), l in [0,16)).
// l<8 -> gate col w*8+l ; l>=8 -> conv col 96 + w*8 + (l-8).
// => lane lm and lane lm+8 of wave w hold a gate/conv PAIR (shfl_xor(8)).
__device__ __forceinline__ int col_perm12(int c) {
  int w = c >> 4, l = c & 15;
  return (l < 8) ? (w * 8 + l) : (96 + w * 8 + l - 8);
}

// ---------------- conversion / sort kernels ----------------
// node features + W in one kernel
__global__ void k_cvt_nw(const float* __restrict__ node, const float* __restrict__ W,
                         unsigned short* __restrict__ nb, unsigned short* __restrict__ Wt) {
  const int NN4 = N_NODES * NF / 4;
  int stride = gridDim.x * blockDim.x;
  for (int i = blockIdx.x * blockDim.x + threadIdx.x; i < NN4 + DOUT * DIN; i += stride) {
    if (i < NN4) {
      float4 v = reinterpret_cast<const float4*>(node)[i];
      ushort4 o;
      o.x = f2bf(v.x); o.y = f2bf(v.y); o.z = f2bf(v.z); o.w = f2bf(v.w);
      reinterpret_cast<ushort4*>(nb)[i] = o;
    } else {
      int j = i - NN4;
      int c = j / DIN, k = j % DIN;
      Wt[j] = f2bf(W[k * DOUT + col_perm12(c)]);
    }
  }
}

// edge features + idx1 histogram in one kernel
__global__ void k_cvt_e(const float* __restrict__ edge, const int* __restrict__ idx1,
                        unsigned short* __restrict__ eb, int* __restrict__ icounts) {
  const int NE4 = N_EDGES * FE / 4;
  int stride = gridDim.x * blockDim.x;
  for (int i = blockIdx.x * blockDim.x + threadIdx.x; i < NE4; i += stride) {
    float4 v = reinterpret_cast<const float4*>(edge)[i];
    ushort4 o;
    o.x = f2bf(v.x); o.y = f2bf(v.y); o.z = f2bf(v.z); o.w = f2bf(v.w);
    reinterpret_cast<ushort4*>(eb)[i] = o;
  }
  for (int e = blockIdx.x * blockDim.x + threadIdx.x; e < N_EDGES; e += stride)
    atomicAdd(&icounts[idx1[e]], 1);
}

// ---- 3-phase multi-block exclusive scan of icounts[50000] -> offsets ----
#define SCAN_B 512
#define SCAN_NB 98
__global__ void k_scanA(const int* __restrict__ ic, int* __restrict__ off,
                        int* __restrict__ bsum) {
  __shared__ int tmp[SCAN_B];
  int tid = threadIdx.x, i = blockIdx.x * SCAN_B + tid;
  int v = (i < N_NODES) ? ic[i] : 0;
  tmp[tid] = v;
  __syncthreads();
  for (int o = 1; o < SCAN_B; o <<= 1) {
    int t = (tid >= o) ? tmp[tid - o] : 0;
    __syncthreads();
    tmp[tid] += t;
    __syncthreads();
  }
  if (i < N_NODES) off[i] = tmp[tid] - v;
  if (tid == SCAN_B - 1) bsum[blockIdx.x] = tmp[tid];
}
__global__ void k_scanB(const int* __restrict__ bsum, int* __restrict__ boff) {
  __shared__ int tmp[128];
  int tid = threadIdx.x;
  int v = (tid < SCAN_NB) ? bsum[tid] : 0;
  tmp[tid] = v;
  __syncthreads();
  for (int o = 1; o < 128; o <<= 1) {
    int t = (tid >= o) ? tmp[tid - o] : 0;
    __syncthreads();
    tmp[tid] += t;
    __syncthreads();
  }
  if (tid < SCAN_NB) boff[tid] = tmp[tid] - v;
}
__global__ void k_scanC(int* __restrict__ off, const int* __restrict__ boff) {
  int i = blockIdx.x * SCAN_B + threadIdx.x;
  if (i < N_NODES) off[i] += boff[blockIdx.x];
}

// scatter edge ids into sorted-by-idx1 order; also pre-gather idx2
__global__ void k_perm(const int* __restrict__ idx1, const int* __restrict__ idx2,
                       const int* __restrict__ offsets, int* __restrict__ cursor,
                       int* __restrict__ perm, int* __restrict__ i1s,
                       int* __restrict__ i2s) {
  int stride = gridDim.x * blockDim.x;
  for (int e = blockIdx.x * blockDim.x + threadIdx.x; e < N_EDGES; e += stride) {
    int n = idx1[e];
    int p = offsets[n] + atomicAdd(&cursor[n], 1);
    perm[p] = e;
    i1s[p] = n;
    i2s[p] = idx2[e];
  }
}

// ---------------- shared GEMM machinery (12 waves x 16 cols) ----------------
// 768 threads; 64 rows/tile; A double-buffered 2x32KB; ONE barrier/tile.
// Prefetch of tile t+1 via global_load_lds into buffer p^1 BEFORE COMPUTE(p);
// the vmcnt(0) drain at __syncthreads() completes it. Zero staging VGPRs.
// B fragment re-read from L2 per K-step via asm-opaqued pointer (8 VGPR live).
// LDS: row r linear; slot cs holds global chunk cs^(r&7) (src-side swizzle).

#define GEMM_PROLOGUE()                                                        \
  const int tid = threadIdx.x;                                                 \
  const int lane = tid & 63;                                                   \
  const int w = tid >> 6;                                                      \
  const int lm = lane & 15;                                                    \
  const int hi = lane >> 4;                                                    \
  const size_t wfoff = (size_t)(w * 16 + lm) * DIN + hi * 8;

#define STAGE_TILE(T, P)                                                       \
  {                                                                            \
    const int e0_ = (T) * 64;                                                  \
    _Pragma("unroll") for (int k = 0; k < 3; ++k) {                            \
      if (k < 2 || w < 8) {                                                    \
        int rbase = 2 * w + 24 * k;                                            \
        int r = rbase + (lane >> 5);                                           \
        int g = (lane & 31) ^ (r & 7);                                         \
        int es = e0_ + rperm_(r);                                              \
        int i1 = i1s[es];                                                      \
        int i2 = i2s[es];                                                      \
        int ep = perm[es];                                                     \
        const unsigned short* s0 = nb + (size_t)i1 * NF + g * 8;               \
        const unsigned short* s1 = nb + (size_t)i2 * NF + (g - 12) * 8;        \
        const unsigned short* s2 = eb + (size_t)ep * FE + (g - 24) * 8;        \
        const unsigned short* src = g < 12 ? s0 : (g < 24 ? s1 : s2);          \
        gload_lds16(src, &As[P][rbase * 256]);                                 \
      }                                                                        \
    }                                                                          \
  }

#define COMPUTE_TILE(P)                                                        \
  {                                                                            \
    uintptr_t wp_ = (uintptr_t)Wt;                                             \
    _Pragma("unroll") for (int ks = 0; ks < 8; ++ks) {                         \
      asm volatile("" : "+s"(wp_));                                            \
      const unsigned short* Wo = (const unsigned short*)wp_;                   \
      bf16x8 bfr = *reinterpret_cast<const bf16x8*>(Wo + wfoff + ks * 32);     \
      int slot = (ks * 4 + hi) ^ (lm & 7);                                     \
      {                                                                        \
        bf16x8 a0 = *reinterpret_cast<const bf16x8*>(                          \
            &As[P][(0 * 16 + lm) * 256 + slot * 8]);                           \
        bf16x8 a1 = *reinterpret_cast<const bf16x8*>(                          \
            &As[P][(1 * 16 + lm) * 256 + slot * 8]);                           \
        acc[0] = __builtin_amdgcn_mfma_f32_16x16x32_bf16(a0, bfr, acc[0], 0, 0, 0); \
        acc[1] = __builtin_amdgcn_mfma_f32_16x16x32_bf16(a1, bfr, acc[1], 0, 0, 0); \
      }                                                                        \
      {                                                                        \
        bf16x8 a0 = *reinterpret_cast<const bf16x8*>(                          \
            &As[P][(2 * 16 + lm) * 256 + slot * 8]);                           \
        bf16x8 a1 = *reinterpret_cast<const bf16x8*>(                          \
            &As[P][(3 * 16 + lm) * 256 + slot * 8]);                           \
        acc[2] = __builtin_amdgcn_mfma_f32_16x16x32_bf16(a0, bfr, acc[2], 0, 0, 0); \
        acc[3] = __builtin_amdgcn_mfma_f32_16x16x32_bf16(a1, bfr, acc[3], 0, 0, 0); \
      }                                                                        \
    }                                                                          \
  }

// PASS 0: column stats of y = XW over stride-16 tile subsample (50k edges)
__global__ __launch_bounds__(768, 6) void k_gstats(
    const unsigned short* __restrict__ nb, const unsigned short* __restrict__ eb,
    const unsigned short* __restrict__ Wt, const int* __restrict__ perm,
    const int* __restrict__ i1s, const int* __restrict__ i2s,
    float* __restrict__ colsum, float* __restrict__ colsumsq) {
  __shared__ unsigned short As[2][64 * 256];  // 64 KB
  GEMM_PROLOGUE();
  float s1a = 0.f, s2a = 0.f;

  int s = blockIdx.x;
  int p = 0;
  if (s < NSAMP) STAGE_TILE(s * SSTRIDE, 0);
  __syncthreads();
  for (; s < NSAMP; s += gridDim.x) {
    int ns = s + gridDim.x;
    if (ns < NSAMP) STAGE_TILE(ns * SSTRIDE, p ^ 1);

    f32x4 acc[4];
#pragma unroll
    for (int rf = 0; rf < 4; ++rf) acc[rf] = (f32x4)(0.f);
    COMPUTE_TILE(p);

#pragma unroll
    for (int rf = 0; rf < 4; ++rf)
#pragma unroll
      for (int j = 0; j < 4; ++j) {
        float y = acc[rf][j];
        s1a += y;
        s2a += y * y;
      }
    __syncthreads();
    p ^= 1;
  }

  {
    float s1 = s1a, s2 = s2a;
    s1 += __shfl_xor(s1, 16); s2 += __shfl_xor(s2, 16);
    s1 += __shfl_xor(s1, 32); s2 += __shfl_xor(s2, 32);
    if (lane < 16) {
      atomicAdd(&colsum[w * 16 + lane], s1);
      atomicAdd(&colsumsq[w * 16 + lane], s2);
    }
  }
}

// PASS 1: zhat = y*a1 + b1f; msg = sigmoid(gate)*softplus(conv) via
// cross-lane pair (shfl_xor 8); in-register segmented scatter (lm<8 lanes).
// Epilogue transcendental diet: per lane, ONE exp2 feeds both paths:
//   gate lane: x=-z*log2e, u=1+2^x, v=rcp(u)=sigmoid(z)
//   conv lane: x=-|z|*log2e, u=1+2^x, v=max(z,0)+ln2*log2(u)=softplus(z)
__global__ __launch_bounds__(768, 6) void k_gmsg2(
    const unsigned short* __restrict__ nb, const unsigned short* __restrict__ eb,
    const unsigned short* __restrict__ Wt, const int* __restrict__ perm,
    const int* __restrict__ i1s, const int* __restrict__ i2s,
    const float* __restrict__ a1, const float* __restrict__ b1f,
    float* __restrict__ sums) {
  __shared__ unsigned short As[2][64 * 256];  // 64 KB
  __shared__ int nidl[2][64];                 // 512 B
  GEMM_PROLOGUE();
  const float c0 = a1[w * 16 + lm];
  const float c1 = b1f[w * 16 + lm];
  const int mcol = w * 8 + (lm & 7);  // orig gate/msg column
  const bool isg = (lm < 8);

  int tile = blockIdx.x;
  int p = 0;
  if (tile < NTILES) {
    STAGE_TILE(tile, 0);
    if (tid < 64) nidl[0][tid] = i1s[tile * 64 + tid];
  }
  __syncthreads();
  for (; tile < NTILES; tile += gridDim.x) {
    int nt = tile + gridDim.x;
    if (nt < NTILES) {
      STAGE_TILE(nt, p ^ 1);
      if (tid < 64) nidl[p ^ 1][tid] = i1s[nt * 64 + tid];
    }

    f32x4 acc[4];
#pragma unroll
    for (int rf = 0; rf < 4; ++rf) acc[rf] = (f32x4)(0.f);
    COMPUTE_TILE(p);

    float run = 0.f;
    int curn = nidl[p][hi * 16];
#pragma unroll
    for (int rf = 0; rf < 4; ++rf)
#pragma unroll
      for (int j = 0; j < 4; ++j) {
        int k = rf * 4 + j;
        float z = acc[rf][j] * c0 + c1;
        float x = (isg ? -z : -fabsf(z)) * 1.44269504f;
        float u = 1.f + exp2f(x);
        float v = isg ? __builtin_amdgcn_rcpf(u)
                      : fmaxf(z, 0.f) + 0.69314718f * log2f(u);
        float pp = __shfl_xor(v, 8);
        run += v * pp;
        int nxt = (k < 15) ? nidl[p][hi * 16 + k + 1] : -1;
        if (nxt != curn) {
          if (isg) atomicAdd(&sums[(size_t)curn * NF + mcol], run);
          run = 0.f;
          curn = nxt;
        }
      }
    __syncthreads();
    p ^= 1;
  }
}

// ---------------- BN affine computation ----------------
// stats from the ~50k-edge subsample; blocks >0 zero the sums-head overlay
// region (replaces a separate hipMemsetAsync launch)
__global__ void k_bn1(const float* __restrict__ colsum, const float* __restrict__ colsumsq,
                      const float* __restrict__ gamma1, const float* __restrict__ beta1,
                      float* __restrict__ a1, float* __restrict__ b1f,
                      float* __restrict__ overlay) {
  if (blockIdx.x > 0) {
    int i = (blockIdx.x - 1) * 256 + threadIdx.x;
    if (i < 131072) overlay[i] = 0.f;
    return;
  }
  int c = threadIdx.x;
  if (c < 192) {
    int o = col_perm12(c);
    const float inv_n = 1.f / (float)(NSAMP * 64);
    float my = colsum[c] * inv_n;
    float v = colsumsq[c] * inv_n - my * my;
    float a = gamma1[o] * rsqrtf(v + BN_EPS);
    a1[c] = a;
    b1f[c] = beta1[o] - my * a;  // bias cancels against batch mean
  }
}

__global__ void k_nodestats(const float* __restrict__ sums, const int* __restrict__ icounts,
                            float* __restrict__ colsum2, float* __restrict__ colsumsq2) {
  __shared__ float sh[2][2][96];
  int t = threadIdx.x;  // 192
  int c = t % 96, sub = t / 96;
  float s1 = 0.f, s2 = 0.f;
  int n0 = blockIdx.x * 256;
  for (int r = sub; r < 256; r += 2) {
    int n = n0 + r;
    if (n < N_NODES) {
      float v = sums[(size_t)n * NF + c] / fmaxf((float)icounts[n], 1.f);
      s1 += v; s2 += v * v;
    }
  }
  sh[0][sub][c] = s1; sh[1][sub][c] = s2;
  __syncthreads();
  if (sub == 0) {
    atomicAdd(&colsum2[c], s1 + sh[0][1][c]);
    atomicAdd(&colsumsq2[c], s2 + sh[1][1][c]);
  }
}

__global__ void k_bn2(const float* __restrict__ colsum2, const float* __restrict__ colsumsq2,
                      const float* __restrict__ gamma2, const float* __restrict__ beta2,
                      float* __restrict__ a2, float* __restrict__ b2f) {
  int c = threadIdx.x;
  if (c < 96) {
    float m = colsum2[c] * (1.f / N_NODES);
    float v = colsumsq2[c] * (1.f / N_NODES) - m * m;
    float a = gamma2[c] * rsqrtf(v + BN_EPS);
    a2[c] = a;
    b2f[c] = beta2[c] - m * a;
  }
}

__global__ void k_final(const float* __restrict__ node, const float* __restrict__ sums,
                        const int* __restrict__ icounts, const float* __restrict__ a2,
                        const float* __restrict__ b2f, float* __restrict__ out) {
  int stride = gridDim.x * blockDim.x;
  for (int i = blockIdx.x * blockDim.x + threadIdx.x; i < N_NODES * NF / 4; i += stride) {
    int n = i / 24, c4 = (i % 24) * 4;
    float inv = 1.f / fmaxf((float)icounts[n], 1.f);
    float4 s = reinterpret_cast<const float4*>(sums)[i];
    float4 nf = reinterpret_cast<const float4*>(node)[i];
    float4 o;
    o.x = softplusf_(nf.x + s.x * inv * a2[c4 + 0] + b2f[c4 + 0]);
    o.y = softplusf_(nf.y + s.y * inv * a2[c4 + 1] + b2f[c4 + 1]);
    o.z = softplusf_(nf.z + s.z * inv * a2[c4 + 2] + b2f[c4 + 2]);
    o.w = softplusf_(nf.w + s.w * inv * a2[c4 + 3] + b2f[c4 + 3]);
    reinterpret_cast<float4*>(out)[i] = o;
  }
}

extern "C" void kernel_launch(void* const* d_in, const int* in_sizes, int n_in,
                              void* d_out, int out_size, void* d_ws, size_t ws_size,
                              hipStream_t stream) {
  const float* node = (const float*)d_in[0];
  const float* edge = (const float*)d_in[1];
  const float* W = (const float*)d_in[2];
  const float* gamma1 = (const float*)d_in[4];
  const float* beta1 = (const float*)d_in[5];
  const float* gamma2 = (const float*)d_in[6];
  const float* beta2 = (const float*)d_in[7];
  const int* idx1 = (const int*)d_in[8];
  const int* idx2 = (const int*)d_in[9];
  float* out = (float*)d_out;

  char* ws = (char*)d_ws;
  unsigned short* nb = (unsigned short*)(ws);               //   9,600,000
  unsigned short* eb = (unsigned short*)(ws + 9600000);     // 102,400,000 (orig order)
  unsigned short* Wt = (unsigned short*)(ws + 112000000);   //      98,304
  float* sums = (float*)(ws + 112098304);                   //  19,200,000
  float* stats = (float*)(ws + 131298304);                  //       8,192
  int* icounts = (int*)(ws + 131306496);                    //     200,000
  int* perm = (int*)(ws + 131506496);                       //   3,200,000
  int* i1s = (int*)(ws + 134706496);                        //   3,200,000
  int* i2s = (int*)(ws + 137906496);                        //   3,200,000
  // total 141,106,496 bytes

  // overlay at head of sums (used only before k_gmsg2, re-zeroed in k_bn1)
  int* offsets = (int*)(ws + 112098304);        // 50000 ints
  int* cursor = offsets + 50048;                // 50000 ints

  float* colsum1 = stats;          // 192
  float* colsumsq1 = stats + 192;  // 192
  float* colsum2 = stats + 384;    // 96
  float* colsumsq2 = stats + 480;  // 96
  float* a1 = stats + 576;         // 192
  float* b1f = stats + 768;        // 192
  float* a2 = stats + 960;         // 96
  float* b2f = stats + 1056;       // 96
  int* bsum = (int*)(ws + 131303424);  // 128 ints
  int* boff = (int*)(ws + 131303936);  // 128 ints

  // zero sums (incl. offsets/cursor overlay) + stats + icounts
  (void)hipMemsetAsync(ws + 112098304, 0, 19200000 + 8192 + 200000, stream);

  k_cvt_nw<<<2048, 256, 0, stream>>>(node, W, nb, Wt);
  k_cvt_e<<<2048, 256, 0, stream>>>(edge, idx1, eb, icounts);
  k_scanA<<<SCAN_NB, SCAN_B, 0, stream>>>(icounts, offsets, bsum);
  k_scanB<<<1, 128, 0, stream>>>(bsum, boff);
  k_scanC<<<SCAN_NB, SCAN_B, 0, stream>>>(offsets, boff);
  k_perm<<<1024, 256, 0, stream>>>(idx1, idx2, offsets, cursor, perm, i1s, i2s);

  k_gstats<<<512, 768, 0, stream>>>(nb, eb, Wt, perm, i1s, i2s, colsum1, colsumsq1);
  // block 0: BN1 affine; blocks 1..512: zero the overlay region of sums
  k_bn1<<<513, 256, 0, stream>>>(colsum1, colsumsq1, gamma1, beta1, a1, b1f,
                                 (float*)(ws + 112098304));

  k_gmsg2<<<512, 768, 0, stream>>>(nb, eb, Wt, perm, i1s, i2s, a1, b1f, sums);

  k_nodestats<<<(N_NODES + 255) / 256, 192, 0, stream>>>(sums, icounts, colsum2, colsumsq2);
  k_bn2<<<1, 128, 0, stream>>>(colsum2, colsumsq2, gamma2, beta2, a2, b2f);
  k_final<<<2048, 256, 0, stream>>>(node, sums, icounts, a2, b2f, out);
}

// Round 21
// 460.286 us; speedup vs baseline: 2.0898x; 1.0199x over previous
//
#include <hip/hip_runtime.h>
#include <stddef.h>
#include <stdint.h>

#define N_NODES 50000
#define N_EDGES 800000
#define NF 96
#define FE 64
#define DIN 256
#define DOUT 192
#define BN_EPS 1e-5f
#define NTILES (N_EDGES / 64)
#define SSTRIDE 32                 // stats subsample: every 32nd tile
#define NSAMP (NTILES / SSTRIDE)   // 390 tiles = 24,960 edges

typedef float f32x4 __attribute__((ext_vector_type(4)));
typedef short bf16x8 __attribute__((ext_vector_type(8)));

__device__ __forceinline__ unsigned short f2bf(float f) {
  unsigned int u = __float_as_uint(f);
  return (unsigned short)((u + 0x7fffu + ((u >> 16) & 1u)) >> 16);
}
__device__ __forceinline__ float softplusf_(float x) {
  float t = exp2f(-fabsf(x) * 1.44269504f);
  return fmaxf(x, 0.f) + 0.69314718f * log2f(1.f + t);
}
__device__ __forceinline__ void gload_lds16(const void* g, void* l) {
  __builtin_amdgcn_global_load_lds(
      (const __attribute__((address_space(1))) void*)g,
      (__attribute__((address_space(3))) void*)l, 16, 0, 0);
}

// row permutation: A-row r holds sorted-edge e0 + rperm_(r); swaps rf<->hi so a
// thread's 16 C-fragment values are 16 CONSECUTIVE sorted edges.
__device__ __forceinline__ int rperm_(int r) {
  return ((r >> 2) & 3) * 16 + (r >> 4) * 4 + (r & 3);
}

// 12-wave col mapping: our col c' = w*16 + l (w in [0,12), l in [0,16)).
// l<8 -> gate col w*8+l ; l>=8 -> conv col 96 + w*8 + (l-8).
// => lane lm and lane lm+8 of wave w hold a gate/conv PAIR (shfl_xor(8)).
__device__ __forceinline__ int col_perm12(int c) {
  int w = c >> 4, l = c & 15;
  return (l < 8) ? (w * 8 + l) : (96 + w * 8 + l - 8);
}

// ---------------- conversion / init kernels ----------------
// node features + W conversion, PLUS zeroing of sums/stats/icounts
// (replaces the hipMemsetAsync launch; same-stream order guarantees the
// zeroed icounts precede k_cvt_e's histogram)
__global__ void k_cvt_nw(const float* __restrict__ node, const float* __restrict__ W,
                         unsigned short* __restrict__ nb, unsigned short* __restrict__ Wt,
                         int4* __restrict__ zero_dst, int nzero4) {
  const int NN4 = N_NODES * NF / 4;
  int stride = gridDim.x * blockDim.x;
  for (int i = blockIdx.x * blockDim.x + threadIdx.x; i < NN4 + DOUT * DIN; i += stride) {
    if (i < NN4) {
      float4 v = reinterpret_cast<const float4*>(node)[i];
      ushort4 o;
      o.x = f2bf(v.x); o.y = f2bf(v.y); o.z = f2bf(v.z); o.w = f2bf(v.w);
      reinterpret_cast<ushort4*>(nb)[i] = o;
    } else {
      int j = i - NN4;
      int c = j / DIN, k = j % DIN;
      Wt[j] = f2bf(W[k * DOUT + col_perm12(c)]);
    }
  }
  for (int i = blockIdx.x * blockDim.x + threadIdx.x; i < nzero4; i += stride)
    zero_dst[i] = make_int4(0, 0, 0, 0);
}

// edge features + idx1 histogram in one kernel
__global__ void k_cvt_e(const float* __restrict__ edge, const int* __restrict__ idx1,
                        unsigned short* __restrict__ eb, int* __restrict__ icounts) {
  const int NE4 = N_EDGES * FE / 4;
  int stride = gridDim.x * blockDim.x;
  for (int i = blockIdx.x * blockDim.x + threadIdx.x; i < NE4; i += stride) {
    float4 v = reinterpret_cast<const float4*>(edge)[i];
    ushort4 o;
    o.x = f2bf(v.x); o.y = f2bf(v.y); o.z = f2bf(v.z); o.w = f2bf(v.w);
    reinterpret_cast<ushort4*>(eb)[i] = o;
  }
  for (int e = blockIdx.x * blockDim.x + threadIdx.x; e < N_EDGES; e += stride)
    atomicAdd(&icounts[idx1[e]], 1);
}

// ---- 3-phase multi-block exclusive scan of icounts[50000] -> offsets ----
#define SCAN_B 512
#define SCAN_NB 98
__global__ void k_scanA(const int* __restrict__ ic, int* __restrict__ off,
                        int* __restrict__ bsum) {
  __shared__ int tmp[SCAN_B];
  int tid = threadIdx.x, i = blockIdx.x * SCAN_B + tid;
  int v = (i < N_NODES) ? ic[i] : 0;
  tmp[tid] = v;
  __syncthreads();
  for (int o = 1; o < SCAN_B; o <<= 1) {
    int t = (tid >= o) ? tmp[tid - o] : 0;
    __syncthreads();
    tmp[tid] += t;
    __syncthreads();
  }
  if (i < N_NODES) off[i] = tmp[tid] - v;
  if (tid == SCAN_B - 1) bsum[blockIdx.x] = tmp[tid];
}
__global__ void k_scanB(const int* __restrict__ bsum, int* __restrict__ boff) {
  __shared__ int tmp[128];
  int tid = threadIdx.x;
  int v = (tid < SCAN_NB) ? bsum[tid] : 0;
  tmp[tid] = v;
  __syncthreads();
  for (int o = 1; o < 128; o <<= 1) {
    int t = (tid >= o) ? tmp[tid - o] : 0;
    __syncthreads();
    tmp[tid] += t;
    __syncthreads();
  }
  if (tid < SCAN_NB) boff[tid] = tmp[tid] - v;
}
__global__ void k_scanC(int* __restrict__ off, const int* __restrict__ boff) {
  int i = blockIdx.x * SCAN_B + threadIdx.x;
  if (i < N_NODES) off[i] += boff[blockIdx.x];
}

// scatter edge ids into sorted-by-idx1 order; also pre-gather idx2
__global__ void k_perm(const int* __restrict__ idx1, const int* __restrict__ idx2,
                       const int* __restrict__ offsets, int* __restrict__ cursor,
                       int* __restrict__ perm, int* __restrict__ i1s,
                       int* __restrict__ i2s) {
  int stride = gridDim.x * blockDim.x;
  for (int e = blockIdx.x * blockDim.x + threadIdx.x; e < N_EDGES; e += stride) {
    int n = idx1[e];
    int p = offsets[n] + atomicAdd(&cursor[n], 1);
    perm[p] = e;
    i1s[p] = n;
    i2s[p] = idx2[e];
  }
}

// ---------------- shared GEMM machinery (12 waves x 16 cols) ----------------
// 768 threads; 64 rows/tile; A double-buffered 2x32KB; ONE barrier/tile.
// Prefetch of tile t+1 via global_load_lds into buffer p^1 BEFORE COMPUTE(p);
// the vmcnt(0) drain at __syncthreads() completes it. Zero staging VGPRs.
// B fragment re-read from L2 per K-step via asm-opaqued pointer (8 VGPR live).
// LDS: row r linear; slot cs holds global chunk cs^(r&7) (src-side swizzle).

#define GEMM_PROLOGUE()                                                        \
  const int tid = threadIdx.x;                                                 \
  const int lane = tid & 63;                                                   \
  const int w = tid >> 6;                                                      \
  const int lm = lane & 15;                                                    \
  const int hi = lane >> 4;                                                    \
  const size_t wfoff = (size_t)(w * 16 + lm) * DIN + hi * 8;

#define STAGE_TILE(T, P)                                                       \
  {                                                                            \
    const int e0_ = (T) * 64;                                                  \
    _Pragma("unroll") for (int k = 0; k < 3; ++k) {                            \
      if (k < 2 || w < 8) {                                                    \
        int rbase = 2 * w + 24 * k;                                            \
        int r = rbase + (lane >> 5);                                           \
        int g = (lane & 31) ^ (r & 7);                                         \
        int es = e0_ + rperm_(r);                                              \
        int i1 = i1s[es];                                                      \
        int i2 = i2s[es];                                                      \
        int ep = perm[es];                                                     \
        const unsigned short* s0 = nb + (size_t)i1 * NF + g * 8;               \
        const unsigned short* s1 = nb + (size_t)i2 * NF + (g - 12) * 8;        \
        const unsigned short* s2 = eb + (size_t)ep * FE + (g - 24) * 8;        \
        const unsigned short* src = g < 12 ? s0 : (g < 24 ? s1 : s2);          \
        gload_lds16(src, &As[P][rbase * 256]);                                 \
      }                                                                        \
    }                                                                          \
  }

#define COMPUTE_TILE(P)                                                        \
  {                                                                            \
    uintptr_t wp_ = (uintptr_t)Wt;                                             \
    _Pragma("unroll") for (int ks = 0; ks < 8; ++ks) {                         \
      asm volatile("" : "+s"(wp_));                                            \
      const unsigned short* Wo = (const unsigned short*)wp_;                   \
      bf16x8 bfr = *reinterpret_cast<const bf16x8*>(Wo + wfoff + ks * 32);     \
      int slot = (ks * 4 + hi) ^ (lm & 7);                                     \
      {                                                                        \
        bf16x8 a0 = *reinterpret_cast<const bf16x8*>(                          \
            &As[P][(0 * 16 + lm) * 256 + slot * 8]);                           \
        bf16x8 a1 = *reinterpret_cast<const bf16x8*>(                          \
            &As[P][(1 * 16 + lm) * 256 + slot * 8]);                           \
        acc[0] = __builtin_amdgcn_mfma_f32_16x16x32_bf16(a0, bfr, acc[0], 0, 0, 0); \
        acc[1] = __builtin_amdgcn_mfma_f32_16x16x32_bf16(a1, bfr, acc[1], 0, 0, 0); \
      }                                                                        \
      {                                                                        \
        bf16x8 a0 = *reinterpret_cast<const bf16x8*>(                          \
            &As[P][(2 * 16 + lm) * 256 + slot * 8]);                           \
        bf16x8 a1 = *reinterpret_cast<const bf16x8*>(                          \
            &As[P][(3 * 16 + lm) * 256 + slot * 8]);                           \
        acc[2] = __builtin_amdgcn_mfma_f32_16x16x32_bf16(a0, bfr, acc[2], 0, 0, 0); \
        acc[3] = __builtin_amdgcn_mfma_f32_16x16x32_bf16(a1, bfr, acc[3], 0, 0, 0); \
      }                                                                        \
    }                                                                          \
  }

// PASS 0: column stats of y = XW over stride-32 tile subsample (25k edges)
__global__ __launch_bounds__(768, 6) void k_gstats(
    const unsigned short* __restrict__ nb, const unsigned short* __restrict__ eb,
    const unsigned short* __restrict__ Wt, const int* __restrict__ perm,
    const int* __restrict__ i1s, const int* __restrict__ i2s,
    float* __restrict__ colsum, float* __restrict__ colsumsq) {
  __shared__ unsigned short As[2][64 * 256];  // 64 KB
  GEMM_PROLOGUE();
  float s1a = 0.f, s2a = 0.f;

  int s = blockIdx.x;
  int p = 0;
  if (s < NSAMP) STAGE_TILE(s * SSTRIDE, 0);
  __syncthreads();
  for (; s < NSAMP; s += gridDim.x) {
    int ns = s + gridDim.x;
    if (ns < NSAMP) STAGE_TILE(ns * SSTRIDE, p ^ 1);

    f32x4 acc[4];
#pragma unroll
    for (int rf = 0; rf < 4; ++rf) acc[rf] = (f32x4)(0.f);
    COMPUTE_TILE(p);

#pragma unroll
    for (int rf = 0; rf < 4; ++rf)
#pragma unroll
      for (int j = 0; j < 4; ++j) {
        float y = acc[rf][j];
        s1a += y;
        s2a += y * y;
      }
    __syncthreads();
    p ^= 1;
  }

  {
    float s1 = s1a, s2 = s2a;
    s1 += __shfl_xor(s1, 16); s2 += __shfl_xor(s2, 16);
    s1 += __shfl_xor(s1, 32); s2 += __shfl_xor(s2, 32);
    if (lane < 16) {
      atomicAdd(&colsum[w * 16 + lane], s1);
      atomicAdd(&colsumsq[w * 16 + lane], s2);
    }
  }
}

// PASS 1: zhat = y*a1 + b1f; msg = sigmoid(gate)*softplus(conv) via
// cross-lane pair (shfl_xor 8); in-register segmented scatter (lm<8 lanes).
// One exp2 per lane feeds both activation paths.
__global__ __launch_bounds__(768, 6) void k_gmsg2(
    const unsigned short* __restrict__ nb, const unsigned short* __restrict__ eb,
    const unsigned short* __restrict__ Wt, const int* __restrict__ perm,
    const int* __restrict__ i1s, const int* __restrict__ i2s,
    const float* __restrict__ a1, const float* __restrict__ b1f,
    float* __restrict__ sums) {
  __shared__ unsigned short As[2][64 * 256];  // 64 KB
  __shared__ int nidl[2][64];                 // 512 B
  GEMM_PROLOGUE();
  const float c0 = a1[w * 16 + lm];
  const float c1 = b1f[w * 16 + lm];
  const int mcol = w * 8 + (lm & 7);  // orig gate/msg column
  const bool isg = (lm < 8);

  int tile = blockIdx.x;
  int p = 0;
  if (tile < NTILES) {
    STAGE_TILE(tile, 0);
    if (tid < 64) nidl[0][tid] = i1s[tile * 64 + tid];
  }
  __syncthreads();
  for (; tile < NTILES; tile += gridDim.x) {
    int nt = tile + gridDim.x;
    if (nt < NTILES) {
      STAGE_TILE(nt, p ^ 1);
      if (tid < 64) nidl[p ^ 1][tid] = i1s[nt * 64 + tid];
    }

    f32x4 acc[4];
#pragma unroll
    for (int rf = 0; rf < 4; ++rf) acc[rf] = (f32x4)(0.f);
    COMPUTE_TILE(p);

    float run = 0.f;
    int curn = nidl[p][hi * 16];
#pragma unroll
    for (int rf = 0; rf < 4; ++rf)
#pragma unroll
      for (int j = 0; j < 4; ++j) {
        int k = rf * 4 + j;
        float z = acc[rf][j] * c0 + c1;
        float x = (isg ? -z : -fabsf(z)) * 1.44269504f;
        float u = 1.f + exp2f(x);
        float v = isg ? __builtin_amdgcn_rcpf(u)
                      : fmaxf(z, 0.f) + 0.69314718f * log2f(u);
        float pp = __shfl_xor(v, 8);
        run += v * pp;
        int nxt = (k < 15) ? nidl[p][hi * 16 + k + 1] : -1;
        if (nxt != curn) {
          if (isg) atomicAdd(&sums[(size_t)curn * NF + mcol], run);
          run = 0.f;
          curn = nxt;
        }
      }
    __syncthreads();
    p ^= 1;
  }
}

// ---------------- BN affine computation ----------------
// stats from the ~25k-edge subsample; blocks >0 zero the sums-head overlay
// region (replaces a separate hipMemsetAsync launch)
__global__ void k_bn1(const float* __restrict__ colsum, const float* __restrict__ colsumsq,
                      const float* __restrict__ gamma1, const float* __restrict__ beta1,
                      float* __restrict__ a1, float* __restrict__ b1f,
                      float* __restrict__ overlay) {
  if (blockIdx.x > 0) {
    int i = (blockIdx.x - 1) * 256 + threadIdx.x;
    if (i < 131072) overlay[i] = 0.f;
    return;
  }
  int c = threadIdx.x;
  if (c < 192) {
    int o = col_perm12(c);
    const float inv_n = 1.f / (float)(NSAMP * 64);
    float my = colsum[c] * inv_n;
    float v = colsumsq[c] * inv_n - my * my;
    float a = gamma1[o] * rsqrtf(v + BN_EPS);
    a1[c] = a;
    b1f[c] = beta1[o] - my * a;  // bias cancels against batch mean
  }
}

__global__ void k_nodestats(const float* __restrict__ sums, const int* __restrict__ icounts,
                            float* __restrict__ colsum2, float* __restrict__ colsumsq2) {
  __shared__ float sh[2][2][96];
  int t = threadIdx.x;  // 192
  int c = t % 96, sub = t / 96;
  float s1 = 0.f, s2 = 0.f;
  int n0 = blockIdx.x * 256;
  for (int r = sub; r < 256; r += 2) {
    int n = n0 + r;
    if (n < N_NODES) {
      float v = sums[(size_t)n * NF + c] / fmaxf((float)icounts[n], 1.f);
      s1 += v; s2 += v * v;
    }
  }
  sh[0][sub][c] = s1; sh[1][sub][c] = s2;
  __syncthreads();
  if (sub == 0) {
    atomicAdd(&colsum2[c], s1 + sh[0][1][c]);
    atomicAdd(&colsumsq2[c], s2 + sh[1][1][c]);
  }
}

// final output; BN2 affine computed per-block from colsum2/colsumsq2 (folds
// the former k_bn2 launch — 96 rsqrt per block is trivial)
__global__ void k_final(const float* __restrict__ node, const float* __restrict__ sums,
                        const int* __restrict__ icounts, const float* __restrict__ colsum2,
                        const float* __restrict__ colsumsq2, const float* __restrict__ gamma2,
                        const float* __restrict__ beta2, float* __restrict__ out) {
  __shared__ float a2s[96], b2s[96];
  if (threadIdx.x < 96) {
    int c = threadIdx.x;
    float m = colsum2[c] * (1.f / N_NODES);
    float v = colsumsq2[c] * (1.f / N_NODES) - m * m;
    float a = gamma2[c] * rsqrtf(v + BN_EPS);
    a2s[c] = a;
    b2s[c] = beta2[c] - m * a;
  }
  __syncthreads();
  int stride = gridDim.x * blockDim.x;
  for (int i = blockIdx.x * blockDim.x + threadIdx.x; i < N_NODES * NF / 4; i += stride) {
    int n = i / 24, c4 = (i % 24) * 4;
    float inv = 1.f / fmaxf((float)icounts[n], 1.f);
    float4 s = reinterpret_cast<const float4*>(sums)[i];
    float4 nf = reinterpret_cast<const float4*>(node)[i];
    float4 o;
    o.x = softplusf_(nf.x + s.x * inv * a2s[c4 + 0] + b2s[c4 + 0]);
    o.y = softplusf_(nf.y + s.y * inv * a2s[c4 + 1] + b2s[c4 + 1]);
    o.z = softplusf_(nf.z + s.z * inv * a2s[c4 + 2] + b2s[c4 + 2]);
    o.w = softplusf_(nf.w + s.w * inv * a2s[c4 + 3] + b2s[c4 + 3]);
    reinterpret_cast<float4*>(out)[i] = o;
  }
}

extern "C" void kernel_launch(void* const* d_in, const int* in_sizes, int n_in,
                              void* d_out, int out_size, void* d_ws, size_t ws_size,
                              hipStream_t stream) {
  const float* node = (const float*)d_in[0];
  const float* edge = (const float*)d_in[1];
  const float* W = (const float*)d_in[2];
  const float* gamma1 = (const float*)d_in[4];
  const float* beta1 = (const float*)d_in[5];
  const float* gamma2 = (const float*)d_in[6];
  const float* beta2 = (const float*)d_in[7];
  const int* idx1 = (const int*)d_in[8];
  const int* idx2 = (const int*)d_in[9];
  float* out = (float*)d_out;

  char* ws = (char*)d_ws;
  unsigned short* nb = (unsigned short*)(ws);               //   9,600,000
  unsigned short* eb = (unsigned short*)(ws + 9600000);     // 102,400,000 (orig order)
  unsigned short* Wt = (unsigned short*)(ws + 112000000);   //      98,304
  float* sums = (float*)(ws + 112098304);                   //  19,200,000
  float* stats = (float*)(ws + 131298304);                  //       8,192
  int* icounts = (int*)(ws + 131306496);                    //     200,000
  int* perm = (int*)(ws + 131506496);                       //   3,200,000
  int* i1s = (int*)(ws + 134706496);                        //   3,200,000
  int* i2s = (int*)(ws + 137906496);                        //   3,200,000
  // total 141,106,496 bytes

  // overlay at head of sums (used only before k_gmsg2, re-zeroed in k_bn1)
  int* offsets = (int*)(ws + 112098304);        // 50000 ints
  int* cursor = offsets + 50048;                // 50000 ints

  float* colsum1 = stats;          // 192
  float* colsumsq1 = stats + 192;  // 192
  float* colsum2 = stats + 384;    // 96
  float* colsumsq2 = stats + 480;  // 96
  float* a1 = stats + 576;         // 192
  float* b1f = stats + 768;        // 192
  int* bsum = (int*)(ws + 131303424);  // 128 ints
  int* boff = (int*)(ws + 131303936);  // 128 ints

  // zeroing of sums+stats+icounts (19,408,192 B, 16B-aligned) is folded into
  // k_cvt_nw; no memset launch
  k_cvt_nw<<<2048, 256, 0, stream>>>(node, W, nb, Wt,
                                     (int4*)(ws + 112098304), 19408192 / 16);
  k_cvt_e<<<2048, 256, 0, stream>>>(edge, idx1, eb, icounts);
  k_scanA<<<SCAN_NB, SCAN_B, 0, stream>>>(icounts, offsets, bsum);
  k_scanB<<<1, 128, 0, stream>>>(bsum, boff);
  k_scanC<<<SCAN_NB, SCAN_B, 0, stream>>>(offsets, boff);
  k_perm<<<1024, 256, 0, stream>>>(idx1, idx2, offsets, cursor, perm, i1s, i2s);

  k_gstats<<<512, 768, 0, stream>>>(nb, eb, Wt, perm, i1s, i2s, colsum1, colsumsq1);
  // block 0: BN1 affine; blocks 1..512: zero the overlay region of sums
  k_bn1<<<513, 256, 0, stream>>>(colsum1, colsumsq1, gamma1, beta1, a1, b1f,
                                 (float*)(ws + 112098304));

  k_gmsg2<<<512, 768, 0, stream>>>(nb, eb, Wt, perm, i1s, i2s, a1, b1f, sums);

  k_nodestats<<<(N_NODES + 255) / 256, 192, 0, stream>>>(sums, icounts, colsum2, colsumsq2);
  k_final<<<2048, 256, 0, stream>>>(node, sums, icounts, colsum2, colsumsq2,
                                    gamma2, beta2, out);
}

// Round 22
// 459.176 us; speedup vs baseline: 2.0948x; 1.0024x over previous
//
#include <hip/hip_runtime.h>
#include <stddef.h>
#include <stdint.h>

#define N_NODES 50000
#define N_EDGES 800000
#define NF 96
#define FE 64
#define DIN 256
#define DOUT 192
#define BN_EPS 1e-5f
#define NTILES (N_EDGES / 64)
#define SSTRIDE 32                 // stats subsample: every 32nd tile
#define NSAMP (NTILES / SSTRIDE)   // 390 tiles = 24,960 edges

typedef float f32x4 __attribute__((ext_vector_type(4)));
typedef short bf16x8 __attribute__((ext_vector_type(8)));

__device__ __forceinline__ unsigned short f2bf(float f) {
  unsigned int u = __float_as_uint(f);
  return (unsigned short)((u + 0x7fffu + ((u >> 16) & 1u)) >> 16);
}
__device__ __forceinline__ float softplusf_(float x) {
  float t = exp2f(-fabsf(x) * 1.44269504f);
  return fmaxf(x, 0.f) + 0.69314718f * log2f(1.f + t);
}
__device__ __forceinline__ void gload_lds16(const void* g, void* l) {
  __builtin_amdgcn_global_load_lds(
      (const __attribute__((address_space(1))) void*)g,
      (__attribute__((address_space(3))) void*)l, 16, 0, 0);
}

// row permutation: A-row r holds sorted-edge e0 + rperm_(r); swaps rf<->hi so a
// thread's 16 C-fragment values are 16 CONSECUTIVE sorted edges.
__device__ __forceinline__ int rperm_(int r) {
  return ((r >> 2) & 3) * 16 + (r >> 4) * 4 + (r & 3);
}

// 12-wave col mapping: our col c' = w*16 + l (w in [0,12), l in [0,16)).
// l<8 -> gate col w*8+l ; l>=8 -> conv col 96 + w*8 + (l-8).
// => lane lm and lane lm+8 of wave w hold a gate/conv PAIR (shfl_xor(8)).
__device__ __forceinline__ int col_perm12(int c) {
  int w = c >> 4, l = c & 15;
  return (l < 8) ? (w * 8 + l) : (96 + w * 8 + l - 8);
}

// ---------------- conversion / init kernels ----------------
// node features + W conversion, PLUS zeroing of sums/stats/icounts
__global__ void k_cvt_nw(const float* __restrict__ node, const float* __restrict__ W,
                         unsigned short* __restrict__ nb, unsigned short* __restrict__ Wt,
                         int4* __restrict__ zero_dst, int nzero4) {
  const int NN4 = N_NODES * NF / 4;
  int stride = gridDim.x * blockDim.x;
  for (int i = blockIdx.x * blockDim.x + threadIdx.x; i < NN4 + DOUT * DIN; i += stride) {
    if (i < NN4) {
      float4 v = reinterpret_cast<const float4*>(node)[i];
      ushort4 o;
      o.x = f2bf(v.x); o.y = f2bf(v.y); o.z = f2bf(v.z); o.w = f2bf(v.w);
      reinterpret_cast<ushort4*>(nb)[i] = o;
    } else {
      int j = i - NN4;
      int c = j / DIN, k = j % DIN;
      Wt[j] = f2bf(W[k * DOUT + col_perm12(c)]);
    }
  }
  for (int i = blockIdx.x * blockDim.x + threadIdx.x; i < nzero4; i += stride)
    zero_dst[i] = make_int4(0, 0, 0, 0);
}

// edge features + idx1 histogram in one kernel
__global__ void k_cvt_e(const float* __restrict__ edge, const int* __restrict__ idx1,
                        unsigned short* __restrict__ eb, int* __restrict__ icounts) {
  const int NE4 = N_EDGES * FE / 4;
  int stride = gridDim.x * blockDim.x;
  for (int i = blockIdx.x * blockDim.x + threadIdx.x; i < NE4; i += stride) {
    float4 v = reinterpret_cast<const float4*>(edge)[i];
    ushort4 o;
    o.x = f2bf(v.x); o.y = f2bf(v.y); o.z = f2bf(v.z); o.w = f2bf(v.w);
    reinterpret_cast<ushort4*>(eb)[i] = o;
  }
  for (int e = blockIdx.x * blockDim.x + threadIdx.x; e < N_EDGES; e += stride)
    atomicAdd(&icounts[idx1[e]], 1);
}

// ---- 2-phase scan (block-partial + block-sums); boff applied inside k_perm ----
#define SCAN_B 512
#define SCAN_NB 98
__global__ void k_scanA(const int* __restrict__ ic, int* __restrict__ off,
                        int* __restrict__ bsum) {
  __shared__ int tmp[SCAN_B];
  int tid = threadIdx.x, i = blockIdx.x * SCAN_B + tid;
  int v = (i < N_NODES) ? ic[i] : 0;
  tmp[tid] = v;
  __syncthreads();
  for (int o = 1; o < SCAN_B; o <<= 1) {
    int t = (tid >= o) ? tmp[tid - o] : 0;
    __syncthreads();
    tmp[tid] += t;
    __syncthreads();
  }
  if (i < N_NODES) off[i] = tmp[tid] - v;
  if (tid == SCAN_B - 1) bsum[blockIdx.x] = tmp[tid];
}
__global__ void k_scanB(const int* __restrict__ bsum, int* __restrict__ boff) {
  __shared__ int tmp[128];
  int tid = threadIdx.x;
  int v = (tid < SCAN_NB) ? bsum[tid] : 0;
  tmp[tid] = v;
  __syncthreads();
  for (int o = 1; o < 128; o <<= 1) {
    int t = (tid >= o) ? tmp[tid - o] : 0;
    __syncthreads();
    tmp[tid] += t;
    __syncthreads();
  }
  if (tid < SCAN_NB) boff[tid] = tmp[tid] - v;
}

// scatter edge ids into sorted-by-idx1 order; applies block-scan offset
// (folds the former k_scanC launch); also pre-gathers idx2
__global__ void k_perm(const int* __restrict__ idx1, const int* __restrict__ idx2,
                       const int* __restrict__ offsets, const int* __restrict__ boff,
                       int* __restrict__ cursor, int* __restrict__ perm,
                       int* __restrict__ i1s, int* __restrict__ i2s) {
  int stride = gridDim.x * blockDim.x;
  for (int e = blockIdx.x * blockDim.x + threadIdx.x; e < N_EDGES; e += stride) {
    int n = idx1[e];
    int p = offsets[n] + boff[n >> 9] + atomicAdd(&cursor[n], 1);
    perm[p] = e;
    i1s[p] = n;
    i2s[p] = idx2[e];
  }
}

// ---------------- shared GEMM machinery (12 waves x 16 cols) ----------------
// 768 threads; 64 rows/tile; A double-buffered 2x32KB; ONE barrier/tile.
// Prefetch of tile t+1 via global_load_lds into buffer p^1 BEFORE COMPUTE(p);
// the vmcnt(0) drain at __syncthreads() completes it. Zero staging VGPRs.
// B fragment re-read from L2 per K-step via asm-opaqued pointer (8 VGPR live).
// LDS: row r linear; slot cs holds global chunk cs^(r&7) (src-side swizzle).

#define GEMM_PROLOGUE()                                                        \
  const int tid = threadIdx.x;                                                 \
  const int lane = tid & 63;                                                   \
  const int w = tid >> 6;                                                      \
  const int lm = lane & 15;                                                    \
  const int hi = lane >> 4;                                                    \
  const size_t wfoff = (size_t)(w * 16 + lm) * DIN + hi * 8;

#define STAGE_TILE(T, P)                                                       \
  {                                                                            \
    const int e0_ = (T) * 64;                                                  \
    _Pragma("unroll") for (int k = 0; k < 3; ++k) {                            \
      if (k < 2 || w < 8) {                                                    \
        int rbase = 2 * w + 24 * k;                                            \
        int r = rbase + (lane >> 5);                                           \
        int g = (lane & 31) ^ (r & 7);                                         \
        int es = e0_ + rperm_(r);                                              \
        int i1 = i1s[es];                                                      \
        int i2 = i2s[es];                                                      \
        int ep = perm[es];                                                     \
        const unsigned short* s0 = nb + (size_t)i1 * NF + g * 8;               \
        const unsigned short* s1 = nb + (size_t)i2 * NF + (g - 12) * 8;        \
        const unsigned short* s2 = eb + (size_t)ep * FE + (g - 24) * 8;        \
        const unsigned short* src = g < 12 ? s0 : (g < 24 ? s1 : s2);          \
        gload_lds16(src, &As[P][rbase * 256]);                                 \
      }                                                                        \
    }                                                                          \
  }

#define COMPUTE_TILE(P)                                                        \
  {                                                                            \
    uintptr_t wp_ = (uintptr_t)Wt;                                             \
    _Pragma("unroll") for (int ks = 0; ks < 8; ++ks) {                         \
      asm volatile("" : "+s"(wp_));                                            \
      const unsigned short* Wo = (const unsigned short*)wp_;                   \
      bf16x8 bfr = *reinterpret_cast<const bf16x8*>(Wo + wfoff + ks * 32);     \
      int slot = (ks * 4 + hi) ^ (lm & 7);                                     \
      {                                                                        \
        bf16x8 a0 = *reinterpret_cast<const bf16x8*>(                          \
            &As[P][(0 * 16 + lm) * 256 + slot * 8]);                           \
        bf16x8 a1 = *reinterpret_cast<const bf16x8*>(                          \
            &As[P][(1 * 16 + lm) * 256 + slot * 8]);                           \
        acc[0] = __builtin_amdgcn_mfma_f32_16x16x32_bf16(a0, bfr, acc[0], 0, 0, 0); \
        acc[1] = __builtin_amdgcn_mfma_f32_16x16x32_bf16(a1, bfr, acc[1], 0, 0, 0); \
      }                                                                        \
      {                                                                        \
        bf16x8 a0 = *reinterpret_cast<const bf16x8*>(                          \
            &As[P][(2 * 16 + lm) * 256 + slot * 8]);                           \
        bf16x8 a1 = *reinterpret_cast<const bf16x8*>(                          \
            &As[P][(3 * 16 + lm) * 256 + slot * 8]);                           \
        acc[2] = __builtin_amdgcn_mfma_f32_16x16x32_bf16(a0, bfr, acc[2], 0, 0, 0); \
        acc[3] = __builtin_amdgcn_mfma_f32_16x16x32_bf16(a1, bfr, acc[3], 0, 0, 0); \
      }                                                                        \
    }                                                                          \
  }

// PASS 0: column stats of y = XW over stride-32 tile subsample (25k edges)
__global__ __launch_bounds__(768, 6) void k_gstats(
    const unsigned short* __restrict__ nb, const unsigned short* __restrict__ eb,
    const unsigned short* __restrict__ Wt, const int* __restrict__ perm,
    const int* __restrict__ i1s, const int* __restrict__ i2s,
    float* __restrict__ colsum, float* __restrict__ colsumsq) {
  __shared__ unsigned short As[2][64 * 256];  // 64 KB
  GEMM_PROLOGUE();
  float s1a = 0.f, s2a = 0.f;

  int s = blockIdx.x;
  int p = 0;
  if (s < NSAMP) STAGE_TILE(s * SSTRIDE, 0);
  __syncthreads();
  for (; s < NSAMP; s += gridDim.x) {
    int ns = s + gridDim.x;
    if (ns < NSAMP) STAGE_TILE(ns * SSTRIDE, p ^ 1);

    f32x4 acc[4];
#pragma unroll
    for (int rf = 0; rf < 4; ++rf) acc[rf] = (f32x4)(0.f);
    COMPUTE_TILE(p);

#pragma unroll
    for (int rf = 0; rf < 4; ++rf)
#pragma unroll
      for (int j = 0; j < 4; ++j) {
        float y = acc[rf][j];
        s1a += y;
        s2a += y * y;
      }
    __syncthreads();
    p ^= 1;
  }

  {
    float s1 = s1a, s2 = s2a;
    s1 += __shfl_xor(s1, 16); s2 += __shfl_xor(s2, 16);
    s1 += __shfl_xor(s1, 32); s2 += __shfl_xor(s2, 32);
    if (lane < 16) {
      atomicAdd(&colsum[w * 16 + lane], s1);
      atomicAdd(&colsumsq[w * 16 + lane], s2);
    }
  }
}

// PASS 1: zhat = y*a1 + b1f; msg = sigmoid(gate)*softplus(conv) via
// cross-lane pair (shfl_xor 8); in-register segmented scatter (lm<8 lanes).
// One exp2 per lane feeds both activation paths.
__global__ __launch_bounds__(768, 6) void k_gmsg2(
    const unsigned short* __restrict__ nb, const unsigned short* __restrict__ eb,
    const unsigned short* __restrict__ Wt, const int* __restrict__ perm,
    const int* __restrict__ i1s, const int* __restrict__ i2s,
    const float* __restrict__ a1, const float* __restrict__ b1f,
    float* __restrict__ sums) {
  __shared__ unsigned short As[2][64 * 256];  // 64 KB
  __shared__ int nidl[2][64];                 // 512 B
  GEMM_PROLOGUE();
  const float c0 = a1[w * 16 + lm];
  const float c1 = b1f[w * 16 + lm];
  const int mcol = w * 8 + (lm & 7);  // orig gate/msg column
  const bool isg = (lm < 8);

  int tile = blockIdx.x;
  int p = 0;
  if (tile < NTILES) {
    STAGE_TILE(tile, 0);
    if (tid < 64) nidl[0][tid] = i1s[tile * 64 + tid];
  }
  __syncthreads();
  for (; tile < NTILES; tile += gridDim.x) {
    int nt = tile + gridDim.x;
    if (nt < NTILES) {
      STAGE_TILE(nt, p ^ 1);
      if (tid < 64) nidl[p ^ 1][tid] = i1s[nt * 64 + tid];
    }

    f32x4 acc[4];
#pragma unroll
    for (int rf = 0; rf < 4; ++rf) acc[rf] = (f32x4)(0.f);
    COMPUTE_TILE(p);

    float run = 0.f;
    int curn = nidl[p][hi * 16];
#pragma unroll
    for (int rf = 0; rf < 4; ++rf)
#pragma unroll
      for (int j = 0; j < 4; ++j) {
        int k = rf * 4 + j;
        float z = acc[rf][j] * c0 + c1;
        float x = (isg ? -z : -fabsf(z)) * 1.44269504f;
        float u = 1.f + exp2f(x);
        float v = isg ? __builtin_amdgcn_rcpf(u)
                      : fmaxf(z, 0.f) + 0.69314718f * log2f(u);
        float pp = __shfl_xor(v, 8);
        run += v * pp;
        int nxt = (k < 15) ? nidl[p][hi * 16 + k + 1] : -1;
        if (nxt != curn) {
          if (isg) atomicAdd(&sums[(size_t)curn * NF + mcol], run);
          run = 0.f;
          curn = nxt;
        }
      }
    __syncthreads();
    p ^= 1;
  }
}

// ---------------- BN affine computation ----------------
// stats from the ~25k-edge subsample; blocks >0 zero the sums-head overlay
__global__ void k_bn1(const float* __restrict__ colsum, const float* __restrict__ colsumsq,
                      const float* __restrict__ gamma1, const float* __restrict__ beta1,
                      float* __restrict__ a1, float* __restrict__ b1f,
                      float* __restrict__ overlay) {
  if (blockIdx.x > 0) {
    int i = (blockIdx.x - 1) * 256 + threadIdx.x;
    if (i < 131072) overlay[i] = 0.f;
    return;
  }
  int c = threadIdx.x;
  if (c < 192) {
    int o = col_perm12(c);
    const float inv_n = 1.f / (float)(NSAMP * 64);
    float my = colsum[c] * inv_n;
    float v = colsumsq[c] * inv_n - my * my;
    float a = gamma1[o] * rsqrtf(v + BN_EPS);
    a1[c] = a;
    b1f[c] = beta1[o] - my * a;  // bias cancels against batch mean
  }
}

__global__ void k_nodestats(const float* __restrict__ sums, const int* __restrict__ icounts,
                            float* __restrict__ colsum2, float* __restrict__ colsumsq2) {
  __shared__ float sh[2][2][96];
  int t = threadIdx.x;  // 192
  int c = t % 96, sub = t / 96;
  float s1 = 0.f, s2 = 0.f;
  int n0 = blockIdx.x * 256;
  for (int r = sub; r < 256; r += 2) {
    int n = n0 + r;
    if (n < N_NODES) {
      float v = sums[(size_t)n * NF + c] / fmaxf((float)icounts[n], 1.f);
      s1 += v; s2 += v * v;
    }
  }
  sh[0][sub][c] = s1; sh[1][sub][c] = s2;
  __syncthreads();
  if (sub == 0) {
    atomicAdd(&colsum2[c], s1 + sh[0][1][c]);
    atomicAdd(&colsumsq2[c], s2 + sh[1][1][c]);
  }
}

// final output; BN2 affine computed per-block from colsum2/colsumsq2
__global__ void k_final(const float* __restrict__ node, const float* __restrict__ sums,
                        const int* __restrict__ icounts, const float* __restrict__ colsum2,
                        const float* __restrict__ colsumsq2, const float* __restrict__ gamma2,
                        const float* __restrict__ beta2, float* __restrict__ out) {
  __shared__ float a2s[96], b2s[96];
  if (threadIdx.x < 96) {
    int c = threadIdx.x;
    float m = colsum2[c] * (1.f / N_NODES);
    float v = colsumsq2[c] * (1.f / N_NODES) - m * m;
    float a = gamma2[c] * rsqrtf(v + BN_EPS);
    a2s[c] = a;
    b2s[c] = beta2[c] - m * a;
  }
  __syncthreads();
  int stride = gridDim.x * blockDim.x;
  for (int i = blockIdx.x * blockDim.x + threadIdx.x; i < N_NODES * NF / 4; i += stride) {
    int n = i / 24, c4 = (i % 24) * 4;
    float inv = 1.f / fmaxf((float)icounts[n], 1.f);
    float4 s = reinterpret_cast<const float4*>(sums)[i];
    float4 nf = reinterpret_cast<const float4*>(node)[i];
    float4 o;
    o.x = softplusf_(nf.x + s.x * inv * a2s[c4 + 0] + b2s[c4 + 0]);
    o.y = softplusf_(nf.y + s.y * inv * a2s[c4 + 1] + b2s[c4 + 1]);
    o.z = softplusf_(nf.z + s.z * inv * a2s[c4 + 2] + b2s[c4 + 2]);
    o.w = softplusf_(nf.w + s.w * inv * a2s[c4 + 3] + b2s[c4 + 3]);
    reinterpret_cast<float4*>(out)[i] = o;
  }
}

extern "C" void kernel_launch(void* const* d_in, const int* in_sizes, int n_in,
                              void* d_out, int out_size, void* d_ws, size_t ws_size,
                              hipStream_t stream) {
  const float* node = (const float*)d_in[0];
  const float* edge = (const float*)d_in[1];
  const float* W = (const float*)d_in[2];
  const float* gamma1 = (const float*)d_in[4];
  const float* beta1 = (const float*)d_in[5];
  const float* gamma2 = (const float*)d_in[6];
  const float* beta2 = (const float*)d_in[7];
  const int* idx1 = (const int*)d_in[8];
  const int* idx2 = (const int*)d_in[9];
  float* out = (float*)d_out;

  char* ws = (char*)d_ws;
  unsigned short* nb = (unsigned short*)(ws);               //   9,600,000
  unsigned short* eb = (unsigned short*)(ws + 9600000);     // 102,400,000 (orig order)
  unsigned short* Wt = (unsigned short*)(ws + 112000000);   //      98,304
  float* sums = (float*)(ws + 112098304);                   //  19,200,000
  float* stats = (float*)(ws + 131298304);                  //       8,192
  int* icounts = (int*)(ws + 131306496);                    //     200,000
  int* perm = (int*)(ws + 131506496);                       //   3,200,000
  int* i1s = (int*)(ws + 134706496);                        //   3,200,000
  int* i2s = (int*)(ws + 137906496);                        //   3,200,000
  // total 141,106,496 bytes

  // overlay at head of sums (used only before k_gmsg2, re-zeroed in k_bn1)
  int* offsets = (int*)(ws + 112098304);        // 50000 ints
  int* cursor = offsets + 50048;                // 50000 ints

  float* colsum1 = stats;          // 192
  float* colsumsq1 = stats + 192;  // 192
  float* colsum2 = stats + 384;    // 96
  float* colsumsq2 = stats + 480;  // 96
  float* a1 = stats + 576;         // 192
  float* b1f = stats + 768;        // 192
  int* bsum = (int*)(ws + 131303424);  // 128 ints
  int* boff = (int*)(ws + 131303936);  // 128 ints

  // zeroing of sums+stats+icounts (19,408,192 B, 16B-aligned) folded into
  // k_cvt_nw; scanC folded into k_perm; bn2 folded into k_final
  k_cvt_nw<<<2048, 256, 0, stream>>>(node, W, nb, Wt,
                                     (int4*)(ws + 112098304), 19408192 / 16);
  k_cvt_e<<<2048, 256, 0, stream>>>(edge, idx1, eb, icounts);
  k_scanA<<<SCAN_NB, SCAN_B, 0, stream>>>(icounts, offsets, bsum);
  k_scanB<<<1, 128, 0, stream>>>(bsum, boff);
  k_perm<<<1024, 256, 0, stream>>>(idx1, idx2, offsets, boff, cursor, perm, i1s, i2s);

  k_gstats<<<NSAMP, 768, 0, stream>>>(nb, eb, Wt, perm, i1s, i2s, colsum1, colsumsq1);
  // block 0: BN1 affine; blocks 1..512: zero the overlay region of sums
  k_bn1<<<513, 256, 0, stream>>>(colsum1, colsumsq1, gamma1, beta1, a1, b1f,
                                 (float*)(ws + 112098304));

  k_gmsg2<<<512, 768, 0, stream>>>(nb, eb, Wt, perm, i1s, i2s, a1, b1f, sums);

  k_nodestats<<<(N_NODES + 255) / 256, 192, 0, stream>>>(sums, icounts, colsum2, colsumsq2);
  k_final<<<2048, 256, 0, stream>>>(node, sums, icounts, colsum2, colsumsq2,
                                    gamma2, beta2, out);
}